// Round 3
// baseline (2503.956 us; speedup 1.0000x reference)
//
#include <hip/hip_runtime.h>

// Problem constants (from reference): B=4096, D=784, H=16, L=4, R=4, K=8
constexpr int cB   = 4096;
constexpr int cD   = 784;
constexpr int cD1  = 392;
constexpr int cH   = 16;
constexpr int cL   = 4;
constexpr int cR   = 4;
constexpr int cDIN = cD1 + cD;        // 1176
constexpr int cPDIM = cD1 * 3 * 8;    // 9408 = D1 * 3K
#define LOG2PI_F 1.8378770664093453f

__device__ __forceinline__ float fast_sigmoid(float v) {
    return 1.0f / (1.0f + __expf(-v));
}

// log_q[b] = -0.5 * sum(eps^2 + LOG2PI)  — one wave per sample
__global__ void __launch_bounds__(256) logq_init_kernel(const float* __restrict__ eps,
                                                        float* __restrict__ logq) {
    const int wid  = threadIdx.x >> 6;
    const int lane = threadIdx.x & 63;
    const int b = blockIdx.x * 4 + wid;
    const float* e = eps + (size_t)b * cD;
    float sum = 0.f;
    for (int i = lane; i < cD; i += 64) { float v = e[i]; sum += v * v; }
    #pragma unroll
    for (int off = 32; off; off >>= 1) sum += __shfl_xor(sum, off, 64);
    if (lane == 0) logq[b] = -0.5f * sum - 0.5f * (float)cD * LOG2PI_F;
}

// h[b][16] = conditioner MLP on concat(zb, x).  One wave per sample.
__global__ void __launch_bounds__(256) mlp_kernel(
    const float* __restrict__ z, const float* __restrict__ x,
    const float* __restrict__ Win, const float* __restrict__ bin,
    const float* __restrict__ W1, const float* __restrict__ b1,
    const float* __restrict__ W2, const float* __restrict__ b2,
    float* __restrict__ hbuf, int zb_off)
{
    const int wid  = threadIdx.x >> 6;
    const int lane = threadIdx.x & 63;
    const int b = blockIdx.x * 4 + wid;

    float acc[16];
    #pragma unroll
    for (int c = 0; c < 16; ++c) acc[c] = 0.f;

    const float* zrow = z + (size_t)b * cD + zb_off;
    const float* xrow = x + (size_t)b * cD;

    for (int i = lane; i < cDIN; i += 64) {
        float v = (i < cD1) ? zrow[i] : xrow[i - cD1];
        const float4* wr = (const float4*)(Win + (size_t)i * cH);
        float4 w0 = wr[0], w1 = wr[1], w2 = wr[2], w3 = wr[3];
        acc[0]  += v * w0.x; acc[1]  += v * w0.y; acc[2]  += v * w0.z; acc[3]  += v * w0.w;
        acc[4]  += v * w1.x; acc[5]  += v * w1.y; acc[6]  += v * w1.z; acc[7]  += v * w1.w;
        acc[8]  += v * w2.x; acc[9]  += v * w2.y; acc[10] += v * w2.z; acc[11] += v * w2.w;
        acc[12] += v * w3.x; acc[13] += v * w3.y; acc[14] += v * w3.z; acc[15] += v * w3.w;
    }
    #pragma unroll
    for (int c = 0; c < 16; ++c) {
        #pragma unroll
        for (int off = 32; off; off >>= 1) acc[c] += __shfl_xor(acc[c], off, 64);
    }

    // every lane now holds all 16 sums; compute residual blocks redundantly (tiny)
    float h[16];
    #pragma unroll
    for (int c = 0; c < 16; ++c) {
        float t = acc[c] + bin[c];
        h[c] = t * fast_sigmoid(t);
    }
    #pragma unroll
    for (int r = 0; r < cR; ++r) {
        const float* w1r = W1 + r * 256;
        const float* b1r = b1 + r * 16;
        const float* w2r = W2 + r * 256;
        const float* b2r = b2 + r * 16;
        float u[16];
        #pragma unroll
        for (int j = 0; j < 16; ++j) u[j] = b1r[j];
        #pragma unroll
        for (int i = 0; i < 16; ++i) {
            float hv = h[i];
            #pragma unroll
            for (int j = 0; j < 16; ++j) u[j] += hv * w1r[i * 16 + j];
        }
        #pragma unroll
        for (int j = 0; j < 16; ++j) u[j] = u[j] * fast_sigmoid(u[j]);
        float vv[16];
        #pragma unroll
        for (int j = 0; j < 16; ++j) vv[j] = b2r[j];
        #pragma unroll
        for (int i = 0; i < 16; ++i) {
            float uv = u[i];
            #pragma unroll
            for (int j = 0; j < 16; ++j) vv[j] += uv * w2r[i * 16 + j];
        }
        #pragma unroll
        for (int j = 0; j < 16; ++j) h[j] += vv[j];
    }
    if (lane == 0) {
        float4* outp = (float4*)(hbuf + (size_t)b * cH);
        outp[0] = make_float4(h[0],  h[1],  h[2],  h[3]);
        outp[1] = make_float4(h[4],  h[5],  h[6],  h[7]);
        outp[2] = make_float4(h[8],  h[9],  h[10], h[11]);
        outp[3] = make_float4(h[12], h[13], h[14], h[15]);
    }
}

// Stable log-space mixture terms: lc=log cdf, lsf=log sf, lp=log pdf.
// lw = log softmax weights, lis = -log_s, is = exp(lis).
// All intermediates finite for finite x.
__device__ __forceinline__ void mix_logterms(
    float x, const float* __restrict__ lw, const float* __restrict__ mu,
    const float* __restrict__ is, const float* __restrict__ lis,
    float& lc, float& lsf, float& lp)
{
    float a[8], bb[8], c[8];
    #pragma unroll
    for (int k = 0; k < 8; ++k) {
        float t = (x - mu[k]) * is[k];
        float e = __expf(-fabsf(t));
        float l1p = __logf(1.0f + e);          // log1p(e), e in (0,1]
        float lsp = fminf(t, 0.0f) - l1p;      // log sigmoid(t)
        float lsn = -fmaxf(t, 0.0f) - l1p;     // log sigmoid(-t)
        a[k]  = lw[k] + lsp;
        bb[k] = lw[k] + lsn;
        c[k]  = a[k] + lsn + lis[k];
    }
    float ma = a[0], mb = bb[0], mc = c[0];
    #pragma unroll
    for (int k = 1; k < 8; ++k) {
        ma = fmaxf(ma, a[k]); mb = fmaxf(mb, bb[k]); mc = fmaxf(mc, c[k]);
    }
    float sa = 0.f, sb = 0.f, sc = 0.f;
    #pragma unroll
    for (int k = 0; k < 8; ++k) {
        sa += __expf(a[k] - ma);
        sb += __expf(bb[k] - mb);
        sc += __expf(c[k] - mc);
    }
    lc  = ma + __logf(sa);
    lsf = mb + __logf(sb);
    lp  = mc + __logf(sc);
}

// Invert the logistic-mixture logit per (sample b, dim d).
// Block = 256: 4 waves = 4 consecutive d (wave-uniform), lane = b within a 64-sample tile.
__global__ void __launch_bounds__(256) invert_kernel(
    float* __restrict__ z, const float* __restrict__ hbuf,
    const float* __restrict__ Wo, const float* __restrict__ bo,
    float* __restrict__ logq, int za_off)
{
    const int wid  = threadIdx.x >> 6;
    const int lane = threadIdx.x & 63;
    const int d = blockIdx.x * 4 + wid;     // 0..391 (wave-uniform)
    const int b = blockIdx.y * 64 + lane;   // 0..4095

    const float4* hp = (const float4*)(hbuf + (size_t)b * cH);
    float4 h0 = hp[0], h1 = hp[1], h2 = hp[2], h3 = hp[3];
    float hh[16] = {h0.x, h0.y, h0.z, h0.w, h1.x, h1.y, h1.z, h1.w,
                    h2.x, h2.y, h2.z, h2.w, h3.x, h3.y, h3.z, h3.w};

    // p[24] = bo[d*24 + j] + sum_i h[i] * Wo[i*9408 + d*24 + j]   (Wo reads wave-uniform)
    float p[24];
    {
        const float4* bp = (const float4*)(bo + (size_t)d * 24);
        #pragma unroll
        for (int j4 = 0; j4 < 6; ++j4) {
            float4 v = bp[j4];
            p[j4*4+0] = v.x; p[j4*4+1] = v.y; p[j4*4+2] = v.z; p[j4*4+3] = v.w;
        }
        #pragma unroll
        for (int i = 0; i < 16; ++i) {
            float hv = hh[i];
            const float4* wr = (const float4*)(Wo + (size_t)i * cPDIM + (size_t)d * 24);
            #pragma unroll
            for (int j4 = 0; j4 < 6; ++j4) {
                float4 wv = wr[j4];
                p[j4*4+0] += hv * wv.x;
                p[j4*4+1] += hv * wv.y;
                p[j4*4+2] += hv * wv.z;
                p[j4*4+3] += hv * wv.w;
            }
        }
    }

    // softmax weights (linear + log), mu, inv_s (linear + log)
    float w[8], lw[8], mu[8], is[8], lis[8];
    {
        float m = p[0];
        #pragma unroll
        for (int k = 1; k < 8; ++k) m = fmaxf(m, p[k]);
        float s = 0.f;
        #pragma unroll
        for (int k = 0; k < 8; ++k) { w[k] = __expf(p[k] - m); s += w[k]; }
        float rs = 1.0f / s;
        float logS = __logf(s);
        #pragma unroll
        for (int k = 0; k < 8; ++k) {
            lw[k] = p[k] - m - logS;
            w[k] *= rs;
            mu[k] = p[8 + k];
            lis[k] = -p[16 + k];
            is[k] = __expf(lis[k]);
        }
    }

    const float y = z[(size_t)b * cD + za_off + d];

    // Bisection on f(mid) = log(cdf) - log(sf) - y.
    // cdf,sf computed overflow-free (each in [0,1], cdf+sf = 1 so at most one
    // log is -inf; the +-inf < y comparison then takes the correct branch for
    // any y, no clamping needed).
    float lo = -100.f, hi = 100.f;
    for (int it = 0; it < 32; ++it) {
        float mid = 0.5f * (lo + hi);
        float cdf = 0.f, sf = 0.f;
        #pragma unroll
        for (int k = 0; k < 8; ++k) {
            float t = (mid - mu[k]) * is[k];
            float e = __expf(-fabsf(t));     // (0,1], never overflows
            float r = 1.0f / (1.0f + e);
            float sp = (t >= 0.f) ? r : e * r;   // sigmoid(t)
            float sn = (t >= 0.f) ? e * r : r;   // sigmoid(-t)
            cdf += w[k] * sp;
            sf  += w[k] * sn;
        }
        float f = __logf(cdf) - __logf(sf);
        if (f < y) lo = mid; else hi = mid;
    }

    // Exactly 3 unconstrained log-space Newton steps (mirrors the reference).
    // Guard only against non-finite steps; clamp is inert on ref trajectories
    // (ref |z| <= ~454).
    float xv = 0.5f * (lo + hi);
    float lc, lsf, lp;
    #pragma unroll 1
    for (int it = 0; it < 3; ++it) {
        mix_logterms(xv, lw, mu, is, lis, lc, lsf, lp);
        float step = (lc - lsf - y) * __expf(lc + lsf - lp);
        if (!isfinite(step)) step = 0.f;
        xv = xv - step;
        xv = fminf(fmaxf(xv, -1.0e6f), 1.0e6f);
    }
    mix_logterms(xv, lw, mu, is, lis, lc, lsf, lp);
    float ld = lp - lc - lsf;

    z[(size_t)b * cD + za_off + d] = xv;

    // reduce ld over the 4 waves (4 d's) per b, one atomic per (block, b)
    __shared__ float red[256];
    red[threadIdx.x] = ld;
    __syncthreads();
    if (wid == 0) {
        float ssum = red[lane] + red[lane + 64] + red[lane + 128] + red[lane + 192];
        atomicAdd(&logq[b], ssum);
    }
}

extern "C" void kernel_launch(void* const* d_in, const int* in_sizes, int n_in,
                              void* d_out, int out_size, void* d_ws, size_t ws_size,
                              hipStream_t stream) {
    const float* x     = (const float*)d_in[0];
    const float* eps   = (const float*)d_in[1];
    const float* W_in  = (const float*)d_in[2];
    const float* b_in  = (const float*)d_in[3];
    const float* W1    = (const float*)d_in[4];
    const float* b1    = (const float*)d_in[5];
    const float* W2    = (const float*)d_in[6];
    const float* b2    = (const float*)d_in[7];
    const float* W_out = (const float*)d_in[8];
    const float* b_out = (const float*)d_in[9];

    float* z    = (float*)d_out;              // (B, D) working state = output z
    float* logq = z + (size_t)cB * cD;        // (B,)   output log_q
    float* hbuf = (float*)d_ws;               // (B, 16) scratch

    hipMemcpyAsync(z, eps, (size_t)cB * cD * sizeof(float), hipMemcpyDeviceToDevice, stream);
    logq_init_kernel<<<cB / 4, 256, 0, stream>>>(eps, logq);

    for (int l = cL - 1; l >= 0; --l) {
        const int zb_off = (l & 1) ? 0 : cD1;   // zb half offset within z row
        const int za_off = (l & 1) ? cD1 : 0;   // za half (overwritten in place by xa)
        mlp_kernel<<<cB / 4, 256, 0, stream>>>(
            z, x,
            W_in + (size_t)l * cDIN * cH, b_in + (size_t)l * cH,
            W1 + (size_t)l * cR * cH * cH, b1 + (size_t)l * cR * cH,
            W2 + (size_t)l * cR * cH * cH, b2 + (size_t)l * cR * cH,
            hbuf, zb_off);
        invert_kernel<<<dim3(cD1 / 4, cB / 64), 256, 0, stream>>>(
            z, hbuf,
            W_out + (size_t)l * cH * cPDIM, b_out + (size_t)l * cPDIM,
            logq, za_off);
    }
}

// Round 4
// 597.910 us; speedup vs baseline: 4.1878x; 4.1878x over previous
//
#include <hip/hip_runtime.h>
#include <math.h>

// Problem constants (from reference): B=4096, D=784, H=16, L=4, R=4, K=8
constexpr int cB   = 4096;
constexpr int cD   = 784;
constexpr int cD1  = 392;
constexpr int cH   = 16;
constexpr int cL   = 4;
constexpr int cR   = 4;
constexpr int cDIN = cD1 + cD;        // 1176
constexpr int cPDIM = cD1 * 3 * 8;    // 9408 = D1 * 3K
#define LOG2PI_F 1.8378770664093453f

__device__ __forceinline__ float rcpf(float x) { return __builtin_amdgcn_rcpf(x); }

// log_q[b] = -0.5 * sum(eps^2 + LOG2PI)  — one wave per sample
__global__ void __launch_bounds__(256) logq_init_kernel(const float* __restrict__ eps,
                                                        float* __restrict__ logq) {
    const int wid  = threadIdx.x >> 6;
    const int lane = threadIdx.x & 63;
    const int b = blockIdx.x * 4 + wid;
    const float* e = eps + (size_t)b * cD;
    float sum = 0.f;
    for (int i = lane; i < cD; i += 64) { float v = e[i]; sum += v * v; }
    #pragma unroll
    for (int off = 32; off; off >>= 1) sum += __shfl_xor(sum, off, 64);
    if (lane == 0) logq[b] = -0.5f * sum - 0.5f * (float)cD * LOG2PI_F;
}

// h[b][16] = conditioner MLP on concat(zb, x).  One wave per sample.
// Stage 1: strided dot over 1176 inputs with 16-col accumulators.
// Transpose-reduce so lane j (mod 16) owns column j; residual blocks are
// lane-distributed (16 FMAs per 16x16 GEMV via width-16 shuffles) — no
// giant unrolled redundant FMA block, no spill pressure.
__global__ void __launch_bounds__(256) mlp_kernel(
    const float* __restrict__ z, const float* __restrict__ x,
    const float* __restrict__ Win, const float* __restrict__ bin,
    const float* __restrict__ W1, const float* __restrict__ b1,
    const float* __restrict__ W2, const float* __restrict__ b2,
    float* __restrict__ hbuf, int zb_off)
{
    const int wid  = threadIdx.x >> 6;
    const int lane = threadIdx.x & 63;
    const int b = blockIdx.x * 4 + wid;
    const int j = lane & 15;

    float acc[16];
    #pragma unroll
    for (int c = 0; c < 16; ++c) acc[c] = 0.f;

    const float* zrow = z + (size_t)b * cD + zb_off;
    const float* xrow = x + (size_t)b * cD;

    for (int i = lane; i < cDIN; i += 64) {
        float v = (i < cD1) ? zrow[i] : xrow[i - cD1];
        const float4* wr = (const float4*)(Win + (size_t)i * cH);
        float4 w0 = wr[0], w1 = wr[1], w2 = wr[2], w3 = wr[3];
        acc[0]  = fmaf(v, w0.x, acc[0]);  acc[1]  = fmaf(v, w0.y, acc[1]);
        acc[2]  = fmaf(v, w0.z, acc[2]);  acc[3]  = fmaf(v, w0.w, acc[3]);
        acc[4]  = fmaf(v, w1.x, acc[4]);  acc[5]  = fmaf(v, w1.y, acc[5]);
        acc[6]  = fmaf(v, w1.z, acc[6]);  acc[7]  = fmaf(v, w1.w, acc[7]);
        acc[8]  = fmaf(v, w2.x, acc[8]);  acc[9]  = fmaf(v, w2.y, acc[9]);
        acc[10] = fmaf(v, w2.z, acc[10]); acc[11] = fmaf(v, w2.w, acc[11]);
        acc[12] = fmaf(v, w3.x, acc[12]); acc[13] = fmaf(v, w3.y, acc[13]);
        acc[14] = fmaf(v, w3.z, acc[14]); acc[15] = fmaf(v, w3.w, acc[15]);
    }

    // Transpose-reduce: exchange halves at offsets 8,4,2,1 so lane ends with
    // the single column j = lane&15 (partial over its 16-lane group), then
    // finish with xor-16/32 butterflies.
    #pragma unroll
    for (int c = 0; c < 8; ++c) {
        float sent = (lane & 8) ? acc[c] : acc[c + 8];
        float mine = (lane & 8) ? acc[c + 8] : acc[c];
        acc[c] = mine + __shfl_xor(sent, 8, 64);
    }
    #pragma unroll
    for (int c = 0; c < 4; ++c) {
        float sent = (lane & 4) ? acc[c] : acc[c + 4];
        float mine = (lane & 4) ? acc[c + 4] : acc[c];
        acc[c] = mine + __shfl_xor(sent, 4, 64);
    }
    #pragma unroll
    for (int c = 0; c < 2; ++c) {
        float sent = (lane & 2) ? acc[c] : acc[c + 2];
        float mine = (lane & 2) ? acc[c + 2] : acc[c];
        acc[c] = mine + __shfl_xor(sent, 2, 64);
    }
    {
        float sent = (lane & 1) ? acc[0] : acc[1];
        float mine = (lane & 1) ? acc[1] : acc[0];
        acc[0] = mine + __shfl_xor(sent, 1, 64);
    }
    float colsum = acc[0];
    colsum += __shfl_xor(colsum, 16, 64);
    colsum += __shfl_xor(colsum, 32, 64);
    // lane holds full input-GEMV result for column j

    float t0 = colsum + bin[j];
    float hj = t0 * rcpf(1.0f + __expf(-t0));   // square_swish

    #pragma unroll
    for (int r = 0; r < cR; ++r) {
        const float* w1r = W1 + r * 256;
        const float* w2r = W2 + r * 256;
        float u = b1[r * 16 + j];
        #pragma unroll
        for (int i = 0; i < 16; ++i)
            u = fmaf(__shfl(hj, i, 16), w1r[i * 16 + j], u);
        u = u * rcpf(1.0f + __expf(-u));
        float v = b2[r * 16 + j];
        #pragma unroll
        for (int i = 0; i < 16; ++i)
            v = fmaf(__shfl(u, i, 16), w2r[i * 16 + j], v);
        hj += v;
    }
    if (lane < 16) hbuf[(size_t)b * cH + j] = hj;
}

// Stable log-space mixture terms (tail/rescue path only).
__device__ __forceinline__ void mix_logterms(
    float x, const float* __restrict__ lw, const float* __restrict__ is,
    const float* __restrict__ nmuis, const float* __restrict__ lis,
    float& lc, float& lsf, float& lp)
{
    float a[8], bb[8], c[8];
    #pragma unroll
    for (int k = 0; k < 8; ++k) {
        float t = fmaf(x, is[k], nmuis[k]);
        float e = __expf(-fabsf(t));
        float l1p = __logf(1.0f + e);
        float lsp = fminf(t, 0.0f) - l1p;      // log sigmoid(t)
        float lsn = -fmaxf(t, 0.0f) - l1p;     // log sigmoid(-t)
        a[k]  = lw[k] + lsp;
        bb[k] = lw[k] + lsn;
        c[k]  = a[k] + lsn + lis[k];
    }
    float ma = a[0], mb = bb[0], mc = c[0];
    #pragma unroll
    for (int k = 1; k < 8; ++k) {
        ma = fmaxf(ma, a[k]); mb = fmaxf(mb, bb[k]); mc = fmaxf(mc, c[k]);
    }
    float sa = 0.f, sb = 0.f, sc = 0.f;
    #pragma unroll
    for (int k = 0; k < 8; ++k) {
        sa += __expf(a[k] - ma);
        sb += __expf(bb[k] - mb);
        sc += __expf(c[k] - mc);
    }
    lc  = ma + __logf(sa);
    lsf = mb + __logf(sb);
    lp  = mc + __logf(sc);
}

// Invert the logistic-mixture logit per (sample b, dim d).
__global__ void __launch_bounds__(256) invert_kernel(
    float* __restrict__ z, const float* __restrict__ hbuf,
    const float* __restrict__ Wo, const float* __restrict__ bo,
    float* __restrict__ logq, int za_off)
{
    const int wid  = threadIdx.x >> 6;
    const int lane = threadIdx.x & 63;
    const int d = blockIdx.x * 4 + wid;     // wave-uniform
    const int b = blockIdx.y * 64 + lane;

    const float4* hp = (const float4*)(hbuf + (size_t)b * cH);
    float4 h0 = hp[0], h1 = hp[1], h2 = hp[2], h3 = hp[3];
    float hh[16] = {h0.x, h0.y, h0.z, h0.w, h1.x, h1.y, h1.z, h1.w,
                    h2.x, h2.y, h2.z, h2.w, h3.x, h3.y, h3.z, h3.w};

    float p[24];
    {
        const float4* bp = (const float4*)(bo + (size_t)d * 24);
        #pragma unroll
        for (int j4 = 0; j4 < 6; ++j4) {
            float4 v = bp[j4];
            p[j4*4+0] = v.x; p[j4*4+1] = v.y; p[j4*4+2] = v.z; p[j4*4+3] = v.w;
        }
        #pragma unroll
        for (int i = 0; i < 16; ++i) {
            float hv = hh[i];
            const float4* wr = (const float4*)(Wo + (size_t)i * cPDIM + (size_t)d * 24);
            #pragma unroll
            for (int j4 = 0; j4 < 6; ++j4) {
                float4 wv = wr[j4];
                p[j4*4+0] = fmaf(hv, wv.x, p[j4*4+0]);
                p[j4*4+1] = fmaf(hv, wv.y, p[j4*4+1]);
                p[j4*4+2] = fmaf(hv, wv.z, p[j4*4+2]);
                p[j4*4+3] = fmaf(hv, wv.w, p[j4*4+3]);
            }
        }
    }

    // softmax weights, scales; nmuis = -mu*is so t = fma(x, is, nmuis)
    float w[8], lw[8], is[8], nmuis[8], lis[8], wis[8];
    {
        float m = p[0];
        #pragma unroll
        for (int k = 1; k < 8; ++k) m = fmaxf(m, p[k]);
        float s = 0.f;
        #pragma unroll
        for (int k = 0; k < 8; ++k) { w[k] = __expf(p[k] - m); s += w[k]; }
        float rs = rcpf(s);
        float logS = __logf(s);
        #pragma unroll
        for (int k = 0; k < 8; ++k) {
            lw[k] = p[k] - m - logS;
            w[k] *= rs;
            lis[k] = -p[16 + k];
            is[k] = __expf(lis[k]);
            nmuis[k] = -p[8 + k] * is[k];
            wis[k] = w[k] * is[k];
        }
    }

    const float y = z[(size_t)b * cD + za_off + d];

    // sigmoid(y): cdf+sf==1, so  log(cdf)-log(sf) < y  <=>  cdf < sigmoid(y)
    float sy;
    {
        float e = __expf(-fabsf(y));
        float r = rcpf(1.0f + e);
        sy = (y >= 0.f) ? r : e * r;
    }

    // 10 cheap bisections: cdf-only evaluation, log-free predicate
    float lo = -100.f, hi = 100.f;
    #pragma unroll 1
    for (int it = 0; it < 10; ++it) {
        float mid = 0.5f * (lo + hi);
        float cdf = 0.f;
        #pragma unroll
        for (int k = 0; k < 8; ++k) {
            float t = fmaf(mid, is[k], nmuis[k]);
            float e = __expf(-fabsf(t));
            float r = rcpf(1.0f + e);
            float sp = (t >= 0.f) ? r : e * r;
            cdf = fmaf(w[k], sp, cdf);
        }
        if (cdf < sy) lo = mid; else hi = mid;
    }

    const bool tail = (fabsf(y) > 12.0f) | (lo < -99.0f) | (hi > 99.0f);

    float xv, ld;
    if (!tail) {
        // 4 bracket-safeguarded linear-space Newton steps + final eval.
        // All quantities well-scaled here (|y|<=12, root interior).
        xv = 0.5f * (lo + hi);
        float cdf, sf, pdf;
        #pragma unroll 1
        for (int it = 0; it < 4; ++it) {
            cdf = 0.f; sf = 0.f; pdf = 0.f;
            #pragma unroll
            for (int k = 0; k < 8; ++k) {
                float t = fmaf(xv, is[k], nmuis[k]);
                float e = __expf(-fabsf(t));
                float r = rcpf(1.0f + e);
                float a = e * r;
                float sp = (t >= 0.f) ? r : a;
                float sn = (t >= 0.f) ? a : r;
                cdf = fmaf(w[k], sp, cdf);
                sf  = fmaf(w[k], sn, sf);
                pdf = fmaf(wis[k], sp * sn, pdf);
            }
            float f = __logf(cdf) - __logf(sf);
            if (f < y) lo = xv; else hi = xv;
            float step = (f - y) * cdf * sf * rcpf(pdf);
            float xn = xv - step;
            if (!(xn > lo && xn < hi)) xn = 0.5f * (lo + hi);  // NaN/overshoot
            xv = xn;
        }
        cdf = 0.f; sf = 0.f; pdf = 0.f;
        #pragma unroll
        for (int k = 0; k < 8; ++k) {
            float t = fmaf(xv, is[k], nmuis[k]);
            float e = __expf(-fabsf(t));
            float r = rcpf(1.0f + e);
            float a = e * r;
            float sp = (t >= 0.f) ? r : a;
            float sn = (t >= 0.f) ? a : r;
            cdf = fmaf(w[k], sp, cdf);
            sf  = fmaf(w[k], sn, sf);
            pdf = fmaf(wis[k], sp * sn, pdf);
        }
        ld = __logf(pdf) - __logf(cdf) - __logf(sf);
        if (!isfinite(ld)) {   // paranoid rescue (never expected)
            float lc2, lsf2, lp2;
            mix_logterms(xv, lw, is, nmuis, lis, lc2, lsf2, lp2);
            ld = lp2 - lc2 - lsf2;
        }
    } else {
        // Rare tail path — exact round-3 structure (known correct):
        // 24 more bisections with log predicate, 3 log-space Newtons.
        #pragma unroll 1
        for (int it = 0; it < 24; ++it) {
            float mid = 0.5f * (lo + hi);
            float cdf = 0.f, sf = 0.f;
            #pragma unroll
            for (int k = 0; k < 8; ++k) {
                float t = fmaf(mid, is[k], nmuis[k]);
                float e = __expf(-fabsf(t));
                float r = rcpf(1.0f + e);
                float a = e * r;
                cdf = fmaf(w[k], (t >= 0.f) ? r : a, cdf);
                sf  = fmaf(w[k], (t >= 0.f) ? a : r, sf);
            }
            float f = __logf(cdf) - __logf(sf);
            if (f < y) lo = mid; else hi = mid;
        }
        xv = 0.5f * (lo + hi);
        float lc, lsf, lp;
        #pragma unroll 1
        for (int it = 0; it < 3; ++it) {
            mix_logterms(xv, lw, is, nmuis, lis, lc, lsf, lp);
            float step = (lc - lsf - y) * __expf(lc + lsf - lp);
            if (!isfinite(step)) step = 0.f;
            xv = fminf(fmaxf(xv - step, -1.0e6f), 1.0e6f);
        }
        mix_logterms(xv, lw, is, nmuis, lis, lc, lsf, lp);
        ld = lp - lc - lsf;
    }

    z[(size_t)b * cD + za_off + d] = xv;

    __shared__ float red[256];
    red[threadIdx.x] = ld;
    __syncthreads();
    if (wid == 0) {
        float ssum = red[lane] + red[lane + 64] + red[lane + 128] + red[lane + 192];
        atomicAdd(&logq[b], ssum);
    }
}

extern "C" void kernel_launch(void* const* d_in, const int* in_sizes, int n_in,
                              void* d_out, int out_size, void* d_ws, size_t ws_size,
                              hipStream_t stream) {
    const float* x     = (const float*)d_in[0];
    const float* eps   = (const float*)d_in[1];
    const float* W_in  = (const float*)d_in[2];
    const float* b_in  = (const float*)d_in[3];
    const float* W1    = (const float*)d_in[4];
    const float* b1    = (const float*)d_in[5];
    const float* W2    = (const float*)d_in[6];
    const float* b2    = (const float*)d_in[7];
    const float* W_out = (const float*)d_in[8];
    const float* b_out = (const float*)d_in[9];

    float* z    = (float*)d_out;              // (B, D) working state = output z
    float* logq = z + (size_t)cB * cD;        // (B,)   output log_q
    float* hbuf = (float*)d_ws;               // (B, 16) scratch

    hipMemcpyAsync(z, eps, (size_t)cB * cD * sizeof(float), hipMemcpyDeviceToDevice, stream);
    logq_init_kernel<<<cB / 4, 256, 0, stream>>>(eps, logq);

    for (int l = cL - 1; l >= 0; --l) {
        const int zb_off = (l & 1) ? 0 : cD1;   // zb half offset within z row
        const int za_off = (l & 1) ? cD1 : 0;   // za half (overwritten in place by xa)
        mlp_kernel<<<cB / 4, 256, 0, stream>>>(
            z, x,
            W_in + (size_t)l * cDIN * cH, b_in + (size_t)l * cH,
            W1 + (size_t)l * cR * cH * cH, b1 + (size_t)l * cR * cH,
            W2 + (size_t)l * cR * cH * cH, b2 + (size_t)l * cR * cH,
            hbuf, zb_off);
        invert_kernel<<<dim3(cD1 / 4, cB / 64), 256, 0, stream>>>(
            z, hbuf,
            W_out + (size_t)l * cH * cPDIM, b_out + (size_t)l * cPDIM,
            logq, za_off);
    }
}

// Round 5
// 469.726 us; speedup vs baseline: 5.3307x; 1.2729x over previous
//
#include <hip/hip_runtime.h>
#include <math.h>

// Problem constants (from reference): B=4096, D=784, H=16, L=4, R=4, K=8
constexpr int cB   = 4096;
constexpr int cD   = 784;
constexpr int cD1  = 392;
constexpr int cH   = 16;
constexpr int cL   = 4;
constexpr int cR   = 4;
constexpr int cDIN = cD1 + cD;        // 1176
constexpr int cPDIM = cD1 * 3 * 8;    // 9408 = D1 * 3K
#define LOG2PI_F 1.8378770664093453f
#define L2E_F    1.4426950408889634f   // log2(e)
#define LN2_F    0.6931471805599453f   // ln(2)
#define LN_LN2_F (-0.36651292058166432701f) // ln(ln 2)

__device__ __forceinline__ float rcpf(float x)  { return __builtin_amdgcn_rcpf(x); }
__device__ __forceinline__ float exp2f_(float x){ return __builtin_amdgcn_exp2f(x); }
__device__ __forceinline__ float log2f_(float x){ return __builtin_amdgcn_logf(x); }
__device__ __forceinline__ float expn(float x)  { return exp2f_(x * L2E_F); }   // e^x
__device__ __forceinline__ float logn(float x)  { return log2f_(x) * LN2_F; }   // ln x

// z[b][:] = eps[b][:];  log_q[b] = -0.5*sum(eps^2 + LOG2PI).  One wave/sample.
__global__ void __launch_bounds__(256) init_kernel(const float* __restrict__ eps,
                                                   float* __restrict__ z,
                                                   float* __restrict__ logq) {
    const int wid  = threadIdx.x >> 6;
    const int lane = threadIdx.x & 63;
    const int b = blockIdx.x * 4 + wid;
    const float* e = eps + (size_t)b * cD;
    float* zr = z + (size_t)b * cD;
    float sum = 0.f;
    for (int i = lane; i < cD; i += 64) {
        float v = e[i];
        zr[i] = v;
        sum = fmaf(v, v, sum);
    }
    #pragma unroll
    for (int off = 32; off; off >>= 1) sum += __shfl_xor(sum, off, 64);
    if (lane == 0) logq[b] = -0.5f * sum - 0.5f * (float)cD * LOG2PI_F;
}

// h[16][b] (transposed) = conditioner MLP on concat(zb, x).  One wave/sample.
__global__ void __launch_bounds__(256) mlp_kernel(
    const float* __restrict__ z, const float* __restrict__ x,
    const float* __restrict__ Win, const float* __restrict__ bin,
    const float* __restrict__ W1, const float* __restrict__ b1,
    const float* __restrict__ W2, const float* __restrict__ b2,
    float* __restrict__ hbuf, int zb_off)
{
    const int wid  = threadIdx.x >> 6;
    const int lane = threadIdx.x & 63;
    const int b = blockIdx.x * 4 + wid;
    const int j = lane & 15;

    float acc[16];
    #pragma unroll
    for (int c = 0; c < 16; ++c) acc[c] = 0.f;

    const float* zrow = z + (size_t)b * cD + zb_off;
    const float* xrow = x + (size_t)b * cD;

    for (int i = lane; i < cDIN; i += 64) {
        float v = (i < cD1) ? zrow[i] : xrow[i - cD1];
        const float4* wr = (const float4*)(Win + (size_t)i * cH);
        float4 w0 = wr[0], w1 = wr[1], w2 = wr[2], w3 = wr[3];
        acc[0]  = fmaf(v, w0.x, acc[0]);  acc[1]  = fmaf(v, w0.y, acc[1]);
        acc[2]  = fmaf(v, w0.z, acc[2]);  acc[3]  = fmaf(v, w0.w, acc[3]);
        acc[4]  = fmaf(v, w1.x, acc[4]);  acc[5]  = fmaf(v, w1.y, acc[5]);
        acc[6]  = fmaf(v, w1.z, acc[6]);  acc[7]  = fmaf(v, w1.w, acc[7]);
        acc[8]  = fmaf(v, w2.x, acc[8]);  acc[9]  = fmaf(v, w2.y, acc[9]);
        acc[10] = fmaf(v, w2.z, acc[10]); acc[11] = fmaf(v, w2.w, acc[11]);
        acc[12] = fmaf(v, w3.x, acc[12]); acc[13] = fmaf(v, w3.y, acc[13]);
        acc[14] = fmaf(v, w3.z, acc[14]); acc[15] = fmaf(v, w3.w, acc[15]);
    }

    // Transpose-reduce: after stages 8,4,2,1 lane holds column j = lane&15
    // summed over its 16-lane group; xor-16/32 finish across groups.
    #pragma unroll
    for (int c = 0; c < 8; ++c) {
        float sent = (lane & 8) ? acc[c] : acc[c + 8];
        float mine = (lane & 8) ? acc[c + 8] : acc[c];
        acc[c] = mine + __shfl_xor(sent, 8, 64);
    }
    #pragma unroll
    for (int c = 0; c < 4; ++c) {
        float sent = (lane & 4) ? acc[c] : acc[c + 4];
        float mine = (lane & 4) ? acc[c + 4] : acc[c];
        acc[c] = mine + __shfl_xor(sent, 4, 64);
    }
    #pragma unroll
    for (int c = 0; c < 2; ++c) {
        float sent = (lane & 2) ? acc[c] : acc[c + 2];
        float mine = (lane & 2) ? acc[c + 2] : acc[c];
        acc[c] = mine + __shfl_xor(sent, 2, 64);
    }
    {
        float sent = (lane & 1) ? acc[0] : acc[1];
        float mine = (lane & 1) ? acc[1] : acc[0];
        acc[0] = mine + __shfl_xor(sent, 1, 64);
    }
    float colsum = acc[0];
    colsum += __shfl_xor(colsum, 16, 64);
    colsum += __shfl_xor(colsum, 32, 64);

    float t0 = colsum + bin[j];
    float hj = t0 * rcpf(1.0f + expn(-t0));   // square_swish

    #pragma unroll
    for (int r = 0; r < cR; ++r) {
        const float* w1r = W1 + r * 256;
        const float* w2r = W2 + r * 256;
        float u = b1[r * 16 + j];
        #pragma unroll
        for (int i = 0; i < 16; ++i)
            u = fmaf(__shfl(hj, i, 16), w1r[i * 16 + j], u);
        u = u * rcpf(1.0f + expn(-u));
        float v = b2[r * 16 + j];
        #pragma unroll
        for (int i = 0; i < 16; ++i)
            v = fmaf(__shfl(u, i, 16), w2r[i * 16 + j], v);
        hj += v;
    }
    if (lane < 16) hbuf[(size_t)j * cB + b] = hj;   // transposed: [16][B]
}

// Invert the logistic-mixture logit per (sample b, dim d).
// Block = 256: 4 waves = 4 consecutive d (wave-uniform), lane = b in a 64-tile.
__global__ void __launch_bounds__(256) invert_kernel(
    float* __restrict__ z, const float* __restrict__ hbuf,
    const float* __restrict__ Wo, const float* __restrict__ bo,
    float* __restrict__ logq, int za_off)
{
    const int wid  = threadIdx.x >> 6;
    const int lane = threadIdx.x & 63;
    const int d = __builtin_amdgcn_readfirstlane(blockIdx.x * 4 + wid); // uniform
    const int b = blockIdx.y * 64 + lane;

    // h: 16 coalesced loads from transposed hbuf
    float hh[16];
    #pragma unroll
    for (int i = 0; i < 16; ++i) hh[i] = hbuf[(size_t)i * cB + b];

    // p[24] = bo[d*24+j] + sum_i h[i]*Wo[i*9408 + d*24 + j]  (Wo wave-uniform)
    float p[24];
    {
        const float4* bp = (const float4*)(bo + (size_t)d * 24);
        #pragma unroll
        for (int j4 = 0; j4 < 6; ++j4) {
            float4 v = bp[j4];
            p[j4*4+0] = v.x; p[j4*4+1] = v.y; p[j4*4+2] = v.z; p[j4*4+3] = v.w;
        }
        #pragma unroll
        for (int i = 0; i < 16; ++i) {
            float hv = hh[i];
            const float4* wr = (const float4*)(Wo + (size_t)i * cPDIM + (size_t)d * 24);
            #pragma unroll
            for (int j4 = 0; j4 < 6; ++j4) {
                float4 wv = wr[j4];
                p[j4*4+0] = fmaf(hv, wv.x, p[j4*4+0]);
                p[j4*4+1] = fmaf(hv, wv.y, p[j4*4+1]);
                p[j4*4+2] = fmaf(hv, wv.z, p[j4*4+2]);
                p[j4*4+3] = fmaf(hv, wv.w, p[j4*4+3]);
            }
        }
    }

    // y and mirror: solve with mu_bar = sgn*mu, y_bar = |y| >= 0; x = sgn*x_bar.
    const float y0  = z[(size_t)b * cD + za_off + d];
    const float sgn = (y0 < 0.f) ? -1.f : 1.f;
    const float yb  = fabsf(y0);

    // mixture params: w (softmax), lw=log w, lis=-log_s, is2=is*log2e,
    // nm2 = -mu_bar*is2.  Exact bracket [min,max] of mu_bar + s*yb.
    float w[8], lw[8], lis[8], is2[8], nm2[8];
    float lo, hi;
    {
        float m = p[0];
        #pragma unroll
        for (int k = 1; k < 8; ++k) m = fmaxf(m, p[k]);
        float s = 0.f;
        #pragma unroll
        for (int k = 0; k < 8; ++k) { w[k] = expn(p[k] - m); s += w[k]; }
        float rs = rcpf(s);
        float lgS = logn(s);
        float lo0 = 1e30f, hi0 = -1e30f;
        #pragma unroll
        for (int k = 0; k < 8; ++k) {
            lw[k] = p[k] - m - lgS;
            w[k] *= rs;
            lis[k] = -p[16 + k];
            float isk = expn(lis[k]);          // 1/s_k
            is2[k] = isk * L2E_F;
            float mub = sgn * p[8 + k];        // mirrored mu
            nm2[k] = -mub * is2[k];
            float inv = fmaf(yb, rcpf(isk), mub);  // mu_bar + s*yb
            lo0 = fminf(lo0, inv); hi0 = fmaxf(hi0, inv);
        }
        float pad = 1e-3f + 1e-5f * (fabsf(lo0) + fabsf(hi0));
        lo = lo0 - pad; hi = hi0 + pad;
    }

    float xv, ld;
    if (yb <= 30.0f) {
        // --- interior: 8 underflow-proof bisections on sf(mid) vs sigmoid(-yb)
        float et  = expn(-yb);
        float tau = et * rcpf(1.0f + et);      // sigmoid(-yb) >= ~5e-14
        #pragma unroll 1
        for (int it = 0; it < 8; ++it) {
            float mid = 0.5f * (lo + hi);
            float sfv = 0.f;
            #pragma unroll
            for (int k = 0; k < 8; ++k) {
                float t2 = fmaf(mid, is2[k], nm2[k]);   // t*log2e
                float e  = exp2f_(-fabsf(t2));
                float r  = rcpf(1.0f + e);
                float sn = (t2 >= 0.f) ? e * r : r;     // sigmoid(-t)
                sfv = fmaf(w[k], sn, sfv);
            }
            if (sfv > tau) lo = mid; else hi = mid;     // sf decreasing in x
        }
        // --- 3 bracketed Newton steps + final ld eval (linear-space, logs of
        // positive sums only; all terms representable for yb<=30)
        xv = 0.5f * (lo + hi);
        #pragma unroll 1
        for (int it = 0; it < 4; ++it) {
            float cdf = 0.f, sfv = 0.f, pdfa = 0.f;
            #pragma unroll
            for (int k = 0; k < 8; ++k) {
                float t2 = fmaf(xv, is2[k], nm2[k]);
                float e  = exp2f_(-fabsf(t2));
                float r  = rcpf(1.0f + e);
                float a  = e * r;
                float sp = (t2 >= 0.f) ? r : a;
                float sn = (t2 >= 0.f) ? a : r;
                cdf  = fmaf(w[k], sp, cdf);
                sfv  = fmaf(w[k], sn, sfv);
                pdfa = fmaf(w[k], sp * sn * is2[k], pdfa);  // pdf = pdfa*ln2
            }
            if (it == 3) {
                ld = (log2f_(pdfa) - log2f_(cdf) - log2f_(sfv)) * LN2_F + LN_LN2_F;
                break;
            }
            float f = (log2f_(cdf) - log2f_(sfv)) * LN2_F;
            if (f < yb) lo = xv; else hi = xv;
            float step = (f - yb) * cdf * sfv * rcpf(pdfa * LN2_F);
            float xn = xv - step;
            if (!(xn > lo && xn < hi)) xn = 0.5f * (lo + hi);
            xv = xn;
        }
    } else {
        // --- tail (yb>30): all t_k > 0 in-bracket; log-space LSE Newton from
        // the exact-bracket midpoint; f is log-linear so 3 steps suffice.
        // lc = log(1 - sf) ~ -e^{-yb} ~ 0 (dropped, error < 1e-13).
        xv = 0.5f * (lo + hi);
        #pragma unroll 1
        for (int it = 0; it < 4; ++it) {
            float u[8];
            float mu_ = -1e30f;
            #pragma unroll
            for (int k = 0; k < 8; ++k) {
                float t  = fmaf(xv, is2[k], nm2[k]) * LN2_F;  // natural t
                float ec = fminf(expn(-t), 1.0f);
                // log sigmoid(-t) = -t - log1p(e^{-t}) ~ -t - (ec - ec^2/2)
                u[k] = lw[k] - t - ec * fmaf(-0.5f, ec, 1.0f);
                mu_ = fmaxf(mu_, u[k]);
            }
            float S = 0.f;
            #pragma unroll
            for (int k = 0; k < 8; ++k) S += expn(u[k] - mu_);
            float lsf = mu_ + logn(S);
            float m2 = -1e30f;
            #pragma unroll
            for (int k = 0; k < 8; ++k) m2 = fmaxf(m2, u[k] + lis[k]);
            float S2 = 0.f;
            #pragma unroll
            for (int k = 0; k < 8; ++k) S2 += expn(u[k] + lis[k] - m2);
            float lp = m2 + logn(S2);
            if (it == 3) { ld = lp - lsf; break; }
            float f = -lsf;                       // lc ~ 0
            if (f < yb) lo = xv; else hi = xv;
            float step = (f - yb) * expn(lsf - lp);
            float xn = xv - step;
            if (!(xn > lo && xn < hi)) xn = 0.5f * (lo + hi);
            xv = xn;
        }
    }

    z[(size_t)b * cD + za_off + d] = sgn * xv;

    // reduce ld over the 4 waves (4 d's) per b, one atomic per (block, b)
    __shared__ float red[256];
    red[threadIdx.x] = ld;
    __syncthreads();
    if (wid == 0) {
        float ssum = red[lane] + red[lane + 64] + red[lane + 128] + red[lane + 192];
        atomicAdd(&logq[b], ssum);
    }
}

extern "C" void kernel_launch(void* const* d_in, const int* in_sizes, int n_in,
                              void* d_out, int out_size, void* d_ws, size_t ws_size,
                              hipStream_t stream) {
    const float* x     = (const float*)d_in[0];
    const float* eps   = (const float*)d_in[1];
    const float* W_in  = (const float*)d_in[2];
    const float* b_in  = (const float*)d_in[3];
    const float* W1    = (const float*)d_in[4];
    const float* b1    = (const float*)d_in[5];
    const float* W2    = (const float*)d_in[6];
    const float* b2    = (const float*)d_in[7];
    const float* W_out = (const float*)d_in[8];
    const float* b_out = (const float*)d_in[9];

    float* z    = (float*)d_out;              // (B, D) working state = output z
    float* logq = z + (size_t)cB * cD;        // (B,)   output log_q
    float* hbuf = (float*)d_ws;               // (16, B) transposed scratch

    init_kernel<<<cB / 4, 256, 0, stream>>>(eps, z, logq);

    for (int l = cL - 1; l >= 0; --l) {
        const int zb_off = (l & 1) ? 0 : cD1;   // zb half offset within z row
        const int za_off = (l & 1) ? cD1 : 0;   // za half (overwritten in place)
        mlp_kernel<<<cB / 4, 256, 0, stream>>>(
            z, x,
            W_in + (size_t)l * cDIN * cH, b_in + (size_t)l * cH,
            W1 + (size_t)l * cR * cH * cH, b1 + (size_t)l * cR * cH,
            W2 + (size_t)l * cR * cH * cH, b2 + (size_t)l * cR * cH,
            hbuf, zb_off);
        invert_kernel<<<dim3(cD1 / 4, cB / 64), 256, 0, stream>>>(
            z, hbuf,
            W_out + (size_t)l * cH * cPDIM, b_out + (size_t)l * cPDIM,
            logq, za_off);
    }
}

// Round 6
// 434.467 us; speedup vs baseline: 5.7633x; 1.0812x over previous
//
#include <hip/hip_runtime.h>
#include <math.h>

// Problem constants (from reference): B=4096, D=784, H=16, L=4, R=4, K=8
constexpr int cB   = 4096;
constexpr int cD   = 784;
constexpr int cD1  = 392;
constexpr int cH   = 16;
constexpr int cL   = 4;
constexpr int cR   = 4;
constexpr int cDIN = cD1 + cD;        // 1176
constexpr int cPDIM = cD1 * 3 * 8;    // 9408 = D1 * 3K
constexpr int CHROWS = 588;           // W_in LDS chunk rows (2 chunks)
#define LOG2PI_F 1.8378770664093453f
#define L2E_F    1.4426950408889634f   // log2(e)
#define LN2_F    0.6931471805599453f   // ln(2)
#define LN_LN2_F (-0.36651292058166432701f) // ln(ln 2)

__device__ __forceinline__ float rcpf(float x)  { return __builtin_amdgcn_rcpf(x); }
__device__ __forceinline__ float exp2f_(float x){ return __builtin_amdgcn_exp2f(x); }
__device__ __forceinline__ float log2f_(float x){ return __builtin_amdgcn_logf(x); }
__device__ __forceinline__ float expn(float x)  { return exp2f_(x * L2E_F); }   // e^x
__device__ __forceinline__ float logn(float x)  { return log2f_(x) * LN2_F; }   // ln x

// z[b][:] = eps[b][:];  log_q[b] = -0.5*sum(eps^2 + LOG2PI).  One wave/sample.
__global__ void __launch_bounds__(256) init_kernel(const float* __restrict__ eps,
                                                   float* __restrict__ z,
                                                   float* __restrict__ logq) {
    const int wid  = threadIdx.x >> 6;
    const int lane = threadIdx.x & 63;
    const int b = blockIdx.x * 4 + wid;
    const float* e = eps + (size_t)b * cD;
    float* zr = z + (size_t)b * cD;
    float sum = 0.f;
    for (int i = lane; i < cD; i += 64) {
        float v = e[i];
        zr[i] = v;
        sum = fmaf(v, v, sum);
    }
    #pragma unroll
    for (int off = 32; off; off >>= 1) sum += __shfl_xor(sum, off, 64);
    if (lane == 0) logq[b] = -0.5f * sum - 0.5f * (float)cD * LOG2PI_F;
}

// h[16][b] (transposed) = conditioner MLP on concat(zb, x).  One wave/sample.
// W_in staged in LDS per block (2 chunks of 588 rows, stride 20 floats:
// 16B-aligned for ds_read_b128, 2-way bank aliasing only).
__global__ void __launch_bounds__(256) mlp_kernel(
    const float* __restrict__ z, const float* __restrict__ x,
    const float* __restrict__ Win, const float* __restrict__ bin,
    const float* __restrict__ W1, const float* __restrict__ b1,
    const float* __restrict__ W2, const float* __restrict__ b2,
    float* __restrict__ hbuf, int zb_off)
{
    __shared__ float ldsw[CHROWS * 20];   // 47040 B
    const int wid  = threadIdx.x >> 6;
    const int lane = threadIdx.x & 63;
    const int b = blockIdx.x * 4 + wid;
    const int j = lane & 15;

    float acc[16];
    #pragma unroll
    for (int c = 0; c < 16; ++c) acc[c] = 0.f;

    const float* zrow = z + (size_t)b * cD + zb_off;
    const float* xrow = x + (size_t)b * cD;

    #pragma unroll 1
    for (int ch = 0; ch < 2; ++ch) {
        const int base = ch * CHROWS;
        __syncthreads();   // protect previous chunk's readers
        for (int t = threadIdx.x; t < CHROWS * 4; t += 256) {
            int i = t >> 2, q = t & 3;
            float4 v = ((const float4*)(Win + (size_t)(base + i) * cH))[q];
            *(float4*)&ldsw[i * 20 + q * 4] = v;
        }
        __syncthreads();
        for (int i = lane; i < CHROWS; i += 64) {
            int gi = base + i;
            float v = (gi < cD1) ? zrow[gi] : xrow[gi - cD1];
            const float4* wr = (const float4*)&ldsw[i * 20];
            float4 w0 = wr[0], w1 = wr[1], w2 = wr[2], w3 = wr[3];
            acc[0]  = fmaf(v, w0.x, acc[0]);  acc[1]  = fmaf(v, w0.y, acc[1]);
            acc[2]  = fmaf(v, w0.z, acc[2]);  acc[3]  = fmaf(v, w0.w, acc[3]);
            acc[4]  = fmaf(v, w1.x, acc[4]);  acc[5]  = fmaf(v, w1.y, acc[5]);
            acc[6]  = fmaf(v, w1.z, acc[6]);  acc[7]  = fmaf(v, w1.w, acc[7]);
            acc[8]  = fmaf(v, w2.x, acc[8]);  acc[9]  = fmaf(v, w2.y, acc[9]);
            acc[10] = fmaf(v, w2.z, acc[10]); acc[11] = fmaf(v, w2.w, acc[11]);
            acc[12] = fmaf(v, w3.x, acc[12]); acc[13] = fmaf(v, w3.y, acc[13]);
            acc[14] = fmaf(v, w3.z, acc[14]); acc[15] = fmaf(v, w3.w, acc[15]);
        }
    }

    // Transpose-reduce: after stages 8,4,2,1 lane holds column j = lane&15
    // summed over its 16-lane group; xor-16/32 finish across groups.
    #pragma unroll
    for (int c = 0; c < 8; ++c) {
        float sent = (lane & 8) ? acc[c] : acc[c + 8];
        float mine = (lane & 8) ? acc[c + 8] : acc[c];
        acc[c] = mine + __shfl_xor(sent, 8, 64);
    }
    #pragma unroll
    for (int c = 0; c < 4; ++c) {
        float sent = (lane & 4) ? acc[c] : acc[c + 4];
        float mine = (lane & 4) ? acc[c + 4] : acc[c];
        acc[c] = mine + __shfl_xor(sent, 4, 64);
    }
    #pragma unroll
    for (int c = 0; c < 2; ++c) {
        float sent = (lane & 2) ? acc[c] : acc[c + 2];
        float mine = (lane & 2) ? acc[c + 2] : acc[c];
        acc[c] = mine + __shfl_xor(sent, 2, 64);
    }
    {
        float sent = (lane & 1) ? acc[0] : acc[1];
        float mine = (lane & 1) ? acc[1] : acc[0];
        acc[0] = mine + __shfl_xor(sent, 1, 64);
    }
    float colsum = acc[0];
    colsum += __shfl_xor(colsum, 16, 64);
    colsum += __shfl_xor(colsum, 32, 64);

    float t0 = colsum + bin[j];
    float hj = t0 * rcpf(1.0f + expn(-t0));   // square_swish

    #pragma unroll
    for (int r = 0; r < cR; ++r) {
        const float* w1r = W1 + r * 256;
        const float* w2r = W2 + r * 256;
        float u = b1[r * 16 + j];
        #pragma unroll
        for (int i = 0; i < 16; ++i)
            u = fmaf(__shfl(hj, i, 16), w1r[i * 16 + j], u);
        u = u * rcpf(1.0f + expn(-u));
        float v = b2[r * 16 + j];
        #pragma unroll
        for (int i = 0; i < 16; ++i)
            v = fmaf(__shfl(u, i, 16), w2r[i * 16 + j], v);
        hj += v;
    }
    if (lane < 16) hbuf[(size_t)j * cB + b] = hj;   // transposed: [16][B]
}

// Invert the logistic-mixture logit per (sample b, dim d).
// Block = 256: 4 waves = 4 consecutive d (wave-uniform), lane = b in a 64-tile.
__global__ void __launch_bounds__(256) invert_kernel(
    float* __restrict__ z, const float* __restrict__ hbuf,
    const float* __restrict__ Wo, const float* __restrict__ bo,
    float* __restrict__ logq, int za_off)
{
    const int wid  = threadIdx.x >> 6;
    const int lane = threadIdx.x & 63;
    const int d = __builtin_amdgcn_readfirstlane(blockIdx.x * 4 + wid); // uniform
    const int b = blockIdx.y * 64 + lane;

    // h: 16 coalesced loads from transposed hbuf
    float hh[16];
    #pragma unroll
    for (int i = 0; i < 16; ++i) hh[i] = hbuf[(size_t)i * cB + b];

    // p[24] = bo[d*24+j] + sum_i h[i]*Wo[i*9408 + d*24 + j]  (Wo wave-uniform)
    float p[24];
    {
        const float4* bp = (const float4*)(bo + (size_t)d * 24);
        #pragma unroll
        for (int j4 = 0; j4 < 6; ++j4) {
            float4 v = bp[j4];
            p[j4*4+0] = v.x; p[j4*4+1] = v.y; p[j4*4+2] = v.z; p[j4*4+3] = v.w;
        }
        #pragma unroll
        for (int i = 0; i < 16; ++i) {
            float hv = hh[i];
            const float4* wr = (const float4*)(Wo + (size_t)i * cPDIM + (size_t)d * 24);
            #pragma unroll
            for (int j4 = 0; j4 < 6; ++j4) {
                float4 wv = wr[j4];
                p[j4*4+0] = fmaf(hv, wv.x, p[j4*4+0]);
                p[j4*4+1] = fmaf(hv, wv.y, p[j4*4+1]);
                p[j4*4+2] = fmaf(hv, wv.z, p[j4*4+2]);
                p[j4*4+3] = fmaf(hv, wv.w, p[j4*4+3]);
            }
        }
    }

    // Mirror: solve with mu_bar = sgn*mu, yb = |y|; x = sgn*x_bar.
    const float y0  = z[(size_t)b * cD + za_off + d];
    const float sgn = (y0 < 0.f) ? -1.f : 1.f;
    const float yb  = fabsf(y0);

    // Unnormalized softmax weights wt (sum S); per-k prescaled scales.
    float wt[8], pm[8], q2[8], is2[8], nm2[8], wis2[8];
    float S, lgSn, SLN2, lo, hi;
    {
        float m = p[0];
        #pragma unroll
        for (int k = 1; k < 8; ++k) m = fmaxf(m, p[k]);
        S = 0.f;
        #pragma unroll
        for (int k = 0; k < 8; ++k) {
            pm[k] = p[k] - m;
            wt[k] = exp2f_(pm[k] * L2E_F);
            S += wt[k];
        }
        lgSn = log2f_(S) * LN2_F;   // ln S
        SLN2 = S * LN2_F;
        float lo0 = 1e30f, hi0 = -1e30f;
        #pragma unroll
        for (int k = 0; k < 8; ++k) {
            q2[k] = p[16 + k] * L2E_F;          // log2 s_k
            float sk  = exp2f_(q2[k]);          // s_k
            float ik  = exp2f_(-q2[k]);         // 1/s_k
            is2[k] = ik * L2E_F;
            float mub = sgn * p[8 + k];
            nm2[k] = -mub * is2[k];
            wis2[k] = wt[k] * is2[k];
            float inv = fmaf(yb, sk, mub);      // mu_bar + s_k*yb
            lo0 = fminf(lo0, inv); hi0 = fmaxf(hi0, inv);
        }
        float pad = 1e-3f + 1e-5f * (fabsf(lo0) + fabsf(hi0));
        lo = lo0 - pad; hi = hi0 + pad;
    }

    float xv, ld;
    if (yb <= 30.0f) {
        // tau*S with tau = sigmoid(-yb) >= ~5e-14
        float et   = exp2f_(-yb * L2E_F);
        float tauS = et * rcpf(1.0f + et) * S;
        // --- 3 bisections; sn = 1/(1+exp2(t2)) is overflow-exact (inf->0)
        #pragma unroll 1
        for (int it = 0; it < 3; ++it) {
            float mid = 0.5f * (lo + hi);
            float sfv = 0.f;
            #pragma unroll
            for (int k = 0; k < 8; ++k) {
                float t2 = fmaf(mid, is2[k], nm2[k]);
                float e  = exp2f_(t2);
                float r  = rcpf(1.0f + e);
                sfv = fmaf(wt[k], r, sfv);
            }
            if (sfv > tauS) lo = mid; else hi = mid;   // sf decreasing in x
        }
        // --- 4 bracketed Newton steps
        xv = 0.5f * (lo + hi);
        #pragma unroll 1
        for (int it = 0; it < 4; ++it) {
            float cdf = 0.f, sfv = 0.f, pdfa = 0.f;
            #pragma unroll
            for (int k = 0; k < 8; ++k) {
                float t2 = fmaf(xv, is2[k], nm2[k]);
                float e  = exp2f_(-fabsf(t2));
                float r  = rcpf(1.0f + e);
                float a  = e * r;
                float sp = (t2 >= 0.f) ? r : a;
                float sn = (t2 >= 0.f) ? a : r;
                cdf = fmaf(wt[k], sp, cdf);
                sfv = fmaf(wt[k], sn, sfv);
                pdfa = fmaf(wis2[k], sp * sn, pdfa);
            }
            float f = (log2f_(cdf) - log2f_(sfv)) * LN2_F;
            if (f < yb) lo = xv; else hi = xv;
            float step = (f - yb) * cdf * sfv * rcpf(pdfa * SLN2);
            float xn = xv - step;
            if (!(xn > lo && xn < hi)) xn = 0.5f * (lo + hi);
            xv = xn;
        }
        // --- peeled 5th eval: ld at xv (pre-step; step5 ~ eps) + final step
        {
            float cdf = 0.f, sfv = 0.f, pdfa = 0.f;
            #pragma unroll
            for (int k = 0; k < 8; ++k) {
                float t2 = fmaf(xv, is2[k], nm2[k]);
                float e  = exp2f_(-fabsf(t2));
                float r  = rcpf(1.0f + e);
                float a  = e * r;
                float sp = (t2 >= 0.f) ? r : a;
                float sn = (t2 >= 0.f) ? a : r;
                cdf = fmaf(wt[k], sp, cdf);
                sfv = fmaf(wt[k], sn, sfv);
                pdfa = fmaf(wis2[k], sp * sn, pdfa);
            }
            float l2c = log2f_(cdf), l2s = log2f_(sfv), l2p = log2f_(pdfa);
            ld = (l2p - l2c - l2s) * LN2_F + LN_LN2_F + lgSn;
            float f = (l2c - l2s) * LN2_F;
            if (f < yb) lo = xv; else hi = xv;
            float step = (f - yb) * cdf * sfv * rcpf(pdfa * SLN2);
            float xn = xv - step;
            if (!(xn > lo && xn < hi)) xn = 0.5f * (lo + hi);
            xv = xn;
        }
    } else {
        // --- tail (yb>30): log-space LSE Newton from exact-bracket midpoint;
        // lc = log(1-sf) ~ -e^{-yb} ~ 0 (dropped, error < 1e-13).
        float lw[8], lis[8];
        #pragma unroll
        for (int k = 0; k < 8; ++k) {
            lw[k]  = pm[k] - lgSn;       // log softmax weight
            lis[k] = -q2[k] * LN2_F;     // -log s_k
        }
        xv = 0.5f * (lo + hi);
        #pragma unroll 1
        for (int it = 0; it < 4; ++it) {
            float u[8];
            float mu_ = -1e30f;
            #pragma unroll
            for (int k = 0; k < 8; ++k) {
                float t  = fmaf(xv, is2[k], nm2[k]) * LN2_F;  // natural t
                float ec = fminf(expn(-t), 1.0f);
                // log sigmoid(-t) = -t - log1p(e^{-t}) ~ -t - (ec - ec^2/2)
                u[k] = lw[k] - t - ec * fmaf(-0.5f, ec, 1.0f);
                mu_ = fmaxf(mu_, u[k]);
            }
            float Su = 0.f;
            #pragma unroll
            for (int k = 0; k < 8; ++k) Su += expn(u[k] - mu_);
            float lsf = mu_ + logn(Su);
            float m2 = -1e30f;
            #pragma unroll
            for (int k = 0; k < 8; ++k) m2 = fmaxf(m2, u[k] + lis[k]);
            float S2 = 0.f;
            #pragma unroll
            for (int k = 0; k < 8; ++k) S2 += expn(u[k] + lis[k] - m2);
            float lp = m2 + logn(S2);
            if (it == 3) { ld = lp - lsf; break; }
            float f = -lsf;                       // lc ~ 0
            if (f < yb) lo = xv; else hi = xv;
            float step = (f - yb) * expn(lsf - lp);
            float xn = xv - step;
            if (!(xn > lo && xn < hi)) xn = 0.5f * (lo + hi);
            xv = xn;
        }
    }

    z[(size_t)b * cD + za_off + d] = sgn * xv;

    // reduce ld over the 4 waves (4 d's) per b, one atomic per (block, b)
    __shared__ float red[256];
    red[threadIdx.x] = ld;
    __syncthreads();
    if (wid == 0) {
        float ssum = red[lane] + red[lane + 64] + red[lane + 128] + red[lane + 192];
        atomicAdd(&logq[b], ssum);
    }
}

extern "C" void kernel_launch(void* const* d_in, const int* in_sizes, int n_in,
                              void* d_out, int out_size, void* d_ws, size_t ws_size,
                              hipStream_t stream) {
    const float* x     = (const float*)d_in[0];
    const float* eps   = (const float*)d_in[1];
    const float* W_in  = (const float*)d_in[2];
    const float* b_in  = (const float*)d_in[3];
    const float* W1    = (const float*)d_in[4];
    const float* b1    = (const float*)d_in[5];
    const float* W2    = (const float*)d_in[6];
    const float* b2    = (const float*)d_in[7];
    const float* W_out = (const float*)d_in[8];
    const float* b_out = (const float*)d_in[9];

    float* z    = (float*)d_out;              // (B, D) working state = output z
    float* logq = z + (size_t)cB * cD;        // (B,)   output log_q
    float* hbuf = (float*)d_ws;               // (16, B) transposed scratch

    init_kernel<<<cB / 4, 256, 0, stream>>>(eps, z, logq);

    for (int l = cL - 1; l >= 0; --l) {
        const int zb_off = (l & 1) ? 0 : cD1;   // zb half offset within z row
        const int za_off = (l & 1) ? cD1 : 0;   // za half (overwritten in place)
        mlp_kernel<<<cB / 4, 256, 0, stream>>>(
            z, x,
            W_in + (size_t)l * cDIN * cH, b_in + (size_t)l * cH,
            W1 + (size_t)l * cR * cH * cH, b1 + (size_t)l * cR * cH,
            W2 + (size_t)l * cR * cH * cH, b2 + (size_t)l * cR * cH,
            hbuf, zb_off);
        invert_kernel<<<dim3(cD1 / 4, cB / 64), 256, 0, stream>>>(
            z, hbuf,
            W_out + (size_t)l * cH * cPDIM, b_out + (size_t)l * cPDIM,
            logq, za_off);
    }
}

// Round 7
// 376.814 us; speedup vs baseline: 6.6451x; 1.1530x over previous
//
#include <hip/hip_runtime.h>
#include <math.h>

// Problem constants (from reference): B=4096, D=784, H=16, L=4, R=4, K=8
constexpr int cB   = 4096;
constexpr int cD   = 784;
constexpr int cD1  = 392;
constexpr int cH   = 16;
constexpr int cL   = 4;
constexpr int cR   = 4;
constexpr int cDIN = cD1 + cD;        // 1176
constexpr int cPDIM = cD1 * 3 * 8;    // 9408 = D1 * 3K
#define LOG2PI_F 1.8378770664093453f
#define L2E_F    1.4426950408889634f   // log2(e)
#define LN2_F    0.6931471805599453f   // ln(2)
#define LN_LN2_F (-0.36651292058166432701f) // ln(ln 2)

__device__ __forceinline__ float rcpf(float x)  { return __builtin_amdgcn_rcpf(x); }
__device__ __forceinline__ float exp2f_(float x){ return __builtin_amdgcn_exp2f(x); }
__device__ __forceinline__ float log2f_(float x){ return __builtin_amdgcn_logf(x); }
__device__ __forceinline__ float expn(float x)  { return exp2f_(x * L2E_F); }   // e^x
__device__ __forceinline__ float logn(float x)  { return log2f_(x) * LN2_F; }   // ln x

// z[b][:] = eps[b][:];  log_q[b] = -0.5*sum(eps^2 + LOG2PI).  One wave/sample.
__global__ void __launch_bounds__(256) init_kernel(const float* __restrict__ eps,
                                                   float* __restrict__ z,
                                                   float* __restrict__ logq) {
    const int wid  = threadIdx.x >> 6;
    const int lane = threadIdx.x & 63;
    const int b = blockIdx.x * 4 + wid;
    const float* e = eps + (size_t)b * cD;
    float* zr = z + (size_t)b * cD;
    float sum = 0.f;
    for (int i = lane; i < cD; i += 64) {
        float v = e[i];
        zr[i] = v;
        sum = fmaf(v, v, sum);
    }
    #pragma unroll
    for (int off = 32; off; off >>= 1) sum += __shfl_xor(sum, off, 64);
    if (lane == 0) logq[b] = -0.5f * sum - 0.5f * (float)cD * LOG2PI_F;
}

// h[16][b] (transposed) = conditioner MLP on concat(zb, x).
// FOUR samples per wave: W_in row loaded once per iter feeds 64 FMAs
// (4x less redundant W streaming from L2 than wave-per-sample).
// Butterfly then routes sample G to 16-lane group G; residual blocks run
// 4 samples/wave via width-16 shuffles.  16 samples per 256-thr block.
__global__ void __launch_bounds__(256) mlp_kernel(
    const float* __restrict__ z, const float* __restrict__ x,
    const float* __restrict__ Win, const float* __restrict__ bin,
    const float* __restrict__ W1, const float* __restrict__ b1,
    const float* __restrict__ W2, const float* __restrict__ b2,
    float* __restrict__ hbuf, int zb_off)
{
    const int wid  = threadIdx.x >> 6;
    const int lane = threadIdx.x & 63;
    const int bw = blockIdx.x * 16 + wid * 4;   // first of this wave's 4 samples
    const int j = lane & 15;
    const int G = lane >> 4;                    // 16-lane group id 0..3

    float acc[4][16];
    #pragma unroll
    for (int s = 0; s < 4; ++s)
        #pragma unroll
        for (int c = 0; c < 16; ++c) acc[s][c] = 0.f;

    const float* pz[4]; const float* px[4];
    #pragma unroll
    for (int s = 0; s < 4; ++s) {
        pz[s] = z + (size_t)(bw + s) * cD + zb_off;
        px[s] = x + (size_t)(bw + s) * cD - cD1;   // so px[i] valid for i>=cD1
    }

    for (int i = lane; i < cDIN; i += 64) {
        const float4* wr = (const float4*)(Win + (size_t)i * cH);
        float4 w0 = wr[0], w1 = wr[1], w2 = wr[2], w3 = wr[3];
        float wv[16] = {w0.x,w0.y,w0.z,w0.w, w1.x,w1.y,w1.z,w1.w,
                        w2.x,w2.y,w2.z,w2.w, w3.x,w3.y,w3.z,w3.w};
        #pragma unroll
        for (int s = 0; s < 4; ++s) {
            const float* src = (i < cD1) ? pz[s] : px[s];
            float v = src[i];
            #pragma unroll
            for (int c = 0; c < 16; ++c) acc[s][c] = fmaf(v, wv[c], acc[s][c]);
        }
    }

    // Per-sample transpose-reduce (stages 8,4,2,1): lane ends holding col
    // (lane&15) of sample s, partial over its 16-lane group.
    #pragma unroll
    for (int s = 0; s < 4; ++s) {
        #pragma unroll
        for (int c = 0; c < 8; ++c) {
            float sent = (lane & 8) ? acc[s][c] : acc[s][c + 8];
            float mine = (lane & 8) ? acc[s][c + 8] : acc[s][c];
            acc[s][c] = mine + __shfl_xor(sent, 8, 64);
        }
        #pragma unroll
        for (int c = 0; c < 4; ++c) {
            float sent = (lane & 4) ? acc[s][c] : acc[s][c + 4];
            float mine = (lane & 4) ? acc[s][c + 4] : acc[s][c];
            acc[s][c] = mine + __shfl_xor(sent, 4, 64);
        }
        #pragma unroll
        for (int c = 0; c < 2; ++c) {
            float sent = (lane & 2) ? acc[s][c] : acc[s][c + 2];
            float mine = (lane & 2) ? acc[s][c + 2] : acc[s][c];
            acc[s][c] = mine + __shfl_xor(sent, 2, 64);
        }
        {
            float sent = (lane & 1) ? acc[s][0] : acc[s][1];
            float mine = (lane & 1) ? acc[s][1] : acc[s][0];
            acc[s][0] = mine + __shfl_xor(sent, 1, 64);
        }
    }
    // Route sample G to group G while finishing the cross-group reduction.
    const int g4 = (lane >> 4) & 1, g5 = (lane >> 5) & 1;
    float a01, a23, colsum;
    {
        float sent = g4 ? acc[0][0] : acc[1][0];
        float keep = g4 ? acc[1][0] : acc[0][0];
        a01 = keep + __shfl_xor(sent, 16, 64);      // sample g4, over g5-pair
    }
    {
        float sent = g4 ? acc[2][0] : acc[3][0];
        float keep = g4 ? acc[3][0] : acc[2][0];
        a23 = keep + __shfl_xor(sent, 16, 64);      // sample 2+g4
    }
    {
        float sent = g5 ? a01 : a23;
        float keep = g5 ? a23 : a01;
        colsum = keep + __shfl_xor(sent, 32, 64);   // group G holds sample G
    }

    float t0 = colsum + bin[j];
    float hj = t0 * rcpf(1.0f + expn(-t0));   // square_swish

    #pragma unroll
    for (int r = 0; r < cR; ++r) {
        const float* w1r = W1 + r * 256;
        const float* w2r = W2 + r * 256;
        float u = b1[r * 16 + j];
        #pragma unroll
        for (int i = 0; i < 16; ++i)
            u = fmaf(__shfl(hj, i, 16), w1r[i * 16 + j], u);
        u = u * rcpf(1.0f + expn(-u));
        float v = b2[r * 16 + j];
        #pragma unroll
        for (int i = 0; i < 16; ++i)
            v = fmaf(__shfl(u, i, 16), w2r[i * 16 + j], v);
        hj += v;
    }
    hbuf[(size_t)j * cB + (bw + G)] = hj;   // transposed: [16][B]
}

// Invert the logistic-mixture logit per (sample b, dim d).
// Block = 256: 4 waves = 4 consecutive d (wave-uniform), lane = b in a 64-tile.
__global__ void __launch_bounds__(256) invert_kernel(
    float* __restrict__ z, const float* __restrict__ hbuf,
    const float* __restrict__ Wo, const float* __restrict__ bo,
    float* __restrict__ logq, int za_off)
{
    const int wid  = threadIdx.x >> 6;
    const int lane = threadIdx.x & 63;
    const int d = __builtin_amdgcn_readfirstlane(blockIdx.x * 4 + wid); // uniform
    const int b = blockIdx.y * 64 + lane;

    // h: 16 coalesced loads from transposed hbuf
    float hh[16];
    #pragma unroll
    for (int i = 0; i < 16; ++i) hh[i] = hbuf[(size_t)i * cB + b];

    // p[24] = bo[d*24+j] + sum_i h[i]*Wo[i*9408 + d*24 + j]  (Wo wave-uniform)
    float p[24];
    {
        const float4* bp = (const float4*)(bo + (size_t)d * 24);
        #pragma unroll
        for (int j4 = 0; j4 < 6; ++j4) {
            float4 v = bp[j4];
            p[j4*4+0] = v.x; p[j4*4+1] = v.y; p[j4*4+2] = v.z; p[j4*4+3] = v.w;
        }
        #pragma unroll
        for (int i = 0; i < 16; ++i) {
            float hv = hh[i];
            const float4* wr = (const float4*)(Wo + (size_t)i * cPDIM + (size_t)d * 24);
            #pragma unroll
            for (int j4 = 0; j4 < 6; ++j4) {
                float4 wv = wr[j4];
                p[j4*4+0] = fmaf(hv, wv.x, p[j4*4+0]);
                p[j4*4+1] = fmaf(hv, wv.y, p[j4*4+1]);
                p[j4*4+2] = fmaf(hv, wv.z, p[j4*4+2]);
                p[j4*4+3] = fmaf(hv, wv.w, p[j4*4+3]);
            }
        }
    }

    // Mirror: solve with mu_bar = sgn*mu, yb = |y|; x = sgn*x_bar.
    const float y0  = z[(size_t)b * cD + za_off + d];
    const float sgn = (y0 < 0.f) ? -1.f : 1.f;
    const float yb  = fabsf(y0);

    // Unnormalized softmax weights wt (sum S); per-k prescaled scales.
    float wt[8], pm[8], q2[8], is2[8], nm2[8], wis2[8];
    float S, lgSn, SLN2, lo, hi;
    {
        float m = p[0];
        #pragma unroll
        for (int k = 1; k < 8; ++k) m = fmaxf(m, p[k]);
        S = 0.f;
        #pragma unroll
        for (int k = 0; k < 8; ++k) {
            pm[k] = p[k] - m;
            wt[k] = exp2f_(pm[k] * L2E_F);
            S += wt[k];
        }
        lgSn = log2f_(S) * LN2_F;   // ln S
        SLN2 = S * LN2_F;
        float lo0 = 1e30f, hi0 = -1e30f;
        #pragma unroll
        for (int k = 0; k < 8; ++k) {
            q2[k] = p[16 + k] * L2E_F;          // log2 s_k
            float sk  = exp2f_(q2[k]);          // s_k
            float ik  = exp2f_(-q2[k]);         // 1/s_k
            is2[k] = ik * L2E_F;
            float mub = sgn * p[8 + k];
            nm2[k] = -mub * is2[k];
            wis2[k] = wt[k] * is2[k];
            float inv = fmaf(yb, sk, mub);      // mu_bar + s_k*yb
            lo0 = fminf(lo0, inv); hi0 = fmaxf(hi0, inv);
        }
        float pad = 1e-3f + 1e-5f * (fabsf(lo0) + fabsf(hi0));
        lo = lo0 - pad; hi = hi0 + pad;
    }

    float xv, ld;
    if (yb <= 30.0f) {
        // tau*S with tau = sigmoid(-yb) >= ~5e-14
        float et   = exp2f_(-yb * L2E_F);
        float tauS = et * rcpf(1.0f + et) * S;
        // --- 3 bisections; sn = 1/(1+exp2(t2)) is overflow-exact (inf->0)
        #pragma unroll 1
        for (int it = 0; it < 3; ++it) {
            float mid = 0.5f * (lo + hi);
            float sfv = 0.f;
            #pragma unroll
            for (int k = 0; k < 8; ++k) {
                float t2 = fmaf(mid, is2[k], nm2[k]);
                float e  = exp2f_(t2);
                float r  = rcpf(1.0f + e);
                sfv = fmaf(wt[k], r, sfv);
            }
            if (sfv > tauS) lo = mid; else hi = mid;   // sf decreasing in x
        }
        // --- 4 bracketed Newton steps
        xv = 0.5f * (lo + hi);
        #pragma unroll 1
        for (int it = 0; it < 4; ++it) {
            float cdf = 0.f, sfv = 0.f, pdfa = 0.f;
            #pragma unroll
            for (int k = 0; k < 8; ++k) {
                float t2 = fmaf(xv, is2[k], nm2[k]);
                float e  = exp2f_(-fabsf(t2));
                float r  = rcpf(1.0f + e);
                float a  = e * r;
                float sp = (t2 >= 0.f) ? r : a;
                float sn = (t2 >= 0.f) ? a : r;
                cdf = fmaf(wt[k], sp, cdf);
                sfv = fmaf(wt[k], sn, sfv);
                pdfa = fmaf(wis2[k], sp * sn, pdfa);
            }
            float f = (log2f_(cdf) - log2f_(sfv)) * LN2_F;
            if (f < yb) lo = xv; else hi = xv;
            float step = (f - yb) * cdf * sfv * rcpf(pdfa * SLN2);
            float xn = xv - step;
            if (!(xn > lo && xn < hi)) xn = 0.5f * (lo + hi);
            xv = xn;
        }
        // --- peeled 5th eval: ld at xv (pre-step; step5 ~ eps) + final step
        {
            float cdf = 0.f, sfv = 0.f, pdfa = 0.f;
            #pragma unroll
            for (int k = 0; k < 8; ++k) {
                float t2 = fmaf(xv, is2[k], nm2[k]);
                float e  = exp2f_(-fabsf(t2));
                float r  = rcpf(1.0f + e);
                float a  = e * r;
                float sp = (t2 >= 0.f) ? r : a;
                float sn = (t2 >= 0.f) ? a : r;
                cdf = fmaf(wt[k], sp, cdf);
                sfv = fmaf(wt[k], sn, sfv);
                pdfa = fmaf(wis2[k], sp * sn, pdfa);
            }
            float l2c = log2f_(cdf), l2s = log2f_(sfv), l2p = log2f_(pdfa);
            ld = (l2p - l2c - l2s) * LN2_F + LN_LN2_F + lgSn;
            float f = (l2c - l2s) * LN2_F;
            if (f < yb) lo = xv; else hi = xv;
            float step = (f - yb) * cdf * sfv * rcpf(pdfa * SLN2);
            float xn = xv - step;
            if (!(xn > lo && xn < hi)) xn = 0.5f * (lo + hi);
            xv = xn;
        }
    } else {
        // --- tail (yb>30): log-space LSE Newton from exact-bracket midpoint;
        // lc = log(1-sf) ~ -e^{-yb} ~ 0 (dropped, error < 1e-13).
        float lw[8], lis[8];
        #pragma unroll
        for (int k = 0; k < 8; ++k) {
            lw[k]  = pm[k] - lgSn;       // log softmax weight
            lis[k] = -q2[k] * LN2_F;     // -log s_k
        }
        xv = 0.5f * (lo + hi);
        #pragma unroll 1
        for (int it = 0; it < 4; ++it) {
            float u[8];
            float mu_ = -1e30f;
            #pragma unroll
            for (int k = 0; k < 8; ++k) {
                float t  = fmaf(xv, is2[k], nm2[k]) * LN2_F;  // natural t
                float ec = fminf(expn(-t), 1.0f);
                // log sigmoid(-t) = -t - log1p(e^{-t}) ~ -t - (ec - ec^2/2)
                u[k] = lw[k] - t - ec * fmaf(-0.5f, ec, 1.0f);
                mu_ = fmaxf(mu_, u[k]);
            }
            float Su = 0.f;
            #pragma unroll
            for (int k = 0; k < 8; ++k) Su += expn(u[k] - mu_);
            float lsf = mu_ + logn(Su);
            float m2 = -1e30f;
            #pragma unroll
            for (int k = 0; k < 8; ++k) m2 = fmaxf(m2, u[k] + lis[k]);
            float S2 = 0.f;
            #pragma unroll
            for (int k = 0; k < 8; ++k) S2 += expn(u[k] + lis[k] - m2);
            float lp = m2 + logn(S2);
            if (it == 3) { ld = lp - lsf; break; }
            float f = -lsf;                       // lc ~ 0
            if (f < yb) lo = xv; else hi = xv;
            float step = (f - yb) * expn(lsf - lp);
            float xn = xv - step;
            if (!(xn > lo && xn < hi)) xn = 0.5f * (lo + hi);
            xv = xn;
        }
    }

    z[(size_t)b * cD + za_off + d] = sgn * xv;

    // reduce ld over the 4 waves (4 d's) per b, one atomic per (block, b)
    __shared__ float red[256];
    red[threadIdx.x] = ld;
    __syncthreads();
    if (wid == 0) {
        float ssum = red[lane] + red[lane + 64] + red[lane + 128] + red[lane + 192];
        atomicAdd(&logq[b], ssum);
    }
}

extern "C" void kernel_launch(void* const* d_in, const int* in_sizes, int n_in,
                              void* d_out, int out_size, void* d_ws, size_t ws_size,
                              hipStream_t stream) {
    const float* x     = (const float*)d_in[0];
    const float* eps   = (const float*)d_in[1];
    const float* W_in  = (const float*)d_in[2];
    const float* b_in  = (const float*)d_in[3];
    const float* W1    = (const float*)d_in[4];
    const float* b1    = (const float*)d_in[5];
    const float* W2    = (const float*)d_in[6];
    const float* b2    = (const float*)d_in[7];
    const float* W_out = (const float*)d_in[8];
    const float* b_out = (const float*)d_in[9];

    float* z    = (float*)d_out;              // (B, D) working state = output z
    float* logq = z + (size_t)cB * cD;        // (B,)   output log_q
    float* hbuf = (float*)d_ws;               // (16, B) transposed scratch

    init_kernel<<<cB / 4, 256, 0, stream>>>(eps, z, logq);

    for (int l = cL - 1; l >= 0; --l) {
        const int zb_off = (l & 1) ? 0 : cD1;   // zb half offset within z row
        const int za_off = (l & 1) ? cD1 : 0;   // za half (overwritten in place)
        mlp_kernel<<<cB / 16, 256, 0, stream>>>(
            z, x,
            W_in + (size_t)l * cDIN * cH, b_in + (size_t)l * cH,
            W1 + (size_t)l * cR * cH * cH, b1 + (size_t)l * cR * cH,
            W2 + (size_t)l * cR * cH * cH, b2 + (size_t)l * cR * cH,
            hbuf, zb_off);
        invert_kernel<<<dim3(cD1 / 4, cB / 64), 256, 0, stream>>>(
            z, hbuf,
            W_out + (size_t)l * cH * cPDIM, b_out + (size_t)l * cPDIM,
            logq, za_off);
    }
}

// Round 8
// 338.173 us; speedup vs baseline: 7.4044x; 1.1143x over previous
//
#include <hip/hip_runtime.h>
#include <math.h>

// Problem constants (from reference): B=4096, D=784, H=16, L=4, R=4, K=8
constexpr int cB   = 4096;
constexpr int cD   = 784;
constexpr int cD1  = 392;
constexpr int cH   = 16;
constexpr int cL   = 4;
constexpr int cR   = 4;
constexpr int cDIN = 1176;            // D1 + D
constexpr int cPDIM = cD1 * 3 * 8;    // 9408 = D1 * 3K
#define LOG2PI_F 1.8378770664093453f
#define L2E_F    1.4426950408889634f   // log2(e)
#define LN2_F    0.6931471805599453f   // ln(2)
#define LN_LN2_F (-0.36651292058166432701f) // ln(ln 2)

__device__ __forceinline__ float rcpf(float x)  { return __builtin_amdgcn_rcpf(x); }
__device__ __forceinline__ float exp2f_(float x){ return __builtin_amdgcn_exp2f(x); }
__device__ __forceinline__ float log2f_(float x){ return __builtin_amdgcn_logf(x); }
__device__ __forceinline__ float expn(float x)  { return exp2f_(x * L2E_F); }   // e^x
__device__ __forceinline__ float logn(float x)  { return log2f_(x) * LN2_F; }   // ln x

// z[b][:] = eps[b][:];  log_q[b] = -0.5*sum(eps^2 + LOG2PI).  One wave/sample.
__global__ void __launch_bounds__(256) init_kernel(const float* __restrict__ eps,
                                                   float* __restrict__ z,
                                                   float* __restrict__ logq) {
    const int wid  = threadIdx.x >> 6;
    const int lane = threadIdx.x & 63;
    const int b = blockIdx.x * 4 + wid;
    const float4* e = (const float4*)(eps + (size_t)b * cD);
    float4* zr = (float4*)(z + (size_t)b * cD);
    float sum = 0.f;
    for (int i = lane; i < cD / 4; i += 64) {   // 784 = 196 float4
        float4 v = e[i];
        zr[i] = v;
        sum = fmaf(v.x, v.x, sum); sum = fmaf(v.y, v.y, sum);
        sum = fmaf(v.z, v.z, sum); sum = fmaf(v.w, v.w, sum);
    }
    #pragma unroll
    for (int off = 32; off; off >>= 1) sum += __shfl_xor(sum, off, 64);
    if (lane == 0) logq[b] = -0.5f * sum - 0.5f * (float)cD * LOG2PI_F;
}

// h[16][b] (transposed) = conditioner MLP on concat(zb, x).
// v3: 8 samples / block (4 waves).  Wave w: rows [588*(w>>1), +588) for
// samples (w&1)*4 .. +3 — split-K across wave pairs doubles occupancy
// (512 blocks = 2/CU = 2 waves/SIMD) and halves the per-wave K loop.
// Partials meet in 1 KB LDS; waves 0-1 run the residual net for 4 samples
// each via width-16 shuffles.
__global__ void __launch_bounds__(256) mlp_kernel(
    const float* __restrict__ z, const float* __restrict__ x,
    const float* __restrict__ Win, const float* __restrict__ bin,
    const float* __restrict__ W1, const float* __restrict__ b1,
    const float* __restrict__ W2, const float* __restrict__ b2,
    float* __restrict__ hbuf, int zb_off)
{
    __shared__ float part[4][4][16];   // [wave][sample-in-group][col]
    const int wid  = threadIdx.x >> 6;
    const int lane = threadIdx.x & 63;
    const int j = lane & 15;
    const int G = lane >> 4;                      // 16-lane group 0..3
    const int bs = blockIdx.x * 8;                // block's first sample
    const int sb = bs + (wid & 1) * 4;            // wave's first sample
    const int r0 = (wid >> 1) * 588;              // wave's row range start

    float acc[4][16];
    #pragma unroll
    for (int s = 0; s < 4; ++s)
        #pragma unroll
        for (int c = 0; c < 16; ++c) acc[s][c] = 0.f;

    const float* pz[4]; const float* px[4];
    #pragma unroll
    for (int s = 0; s < 4; ++s) {
        pz[s] = z + (size_t)(sb + s) * cD + zb_off;
        px[s] = x + (size_t)(sb + s) * cD - cD1;   // valid for i>=cD1
    }

    for (int i = r0 + lane; i < r0 + 588; i += 64) {
        const float4* wr = (const float4*)(Win + (size_t)i * cH);
        float4 w0 = wr[0], w1 = wr[1], w2 = wr[2], w3 = wr[3];
        float wv[16] = {w0.x,w0.y,w0.z,w0.w, w1.x,w1.y,w1.z,w1.w,
                        w2.x,w2.y,w2.z,w2.w, w3.x,w3.y,w3.z,w3.w};
        #pragma unroll
        for (int s = 0; s < 4; ++s) {
            const float* src = (i < cD1) ? pz[s] : px[s];
            float v = src[i];
            #pragma unroll
            for (int c = 0; c < 16; ++c) acc[s][c] = fmaf(v, wv[c], acc[s][c]);
        }
    }

    // Per-sample transpose-reduce (stages 8,4,2,1): lane ends holding col
    // (lane&15) of sample s, partial over its 16-lane group.
    #pragma unroll
    for (int s = 0; s < 4; ++s) {
        #pragma unroll
        for (int c = 0; c < 8; ++c) {
            float sent = (lane & 8) ? acc[s][c] : acc[s][c + 8];
            float mine = (lane & 8) ? acc[s][c + 8] : acc[s][c];
            acc[s][c] = mine + __shfl_xor(sent, 8, 64);
        }
        #pragma unroll
        for (int c = 0; c < 4; ++c) {
            float sent = (lane & 4) ? acc[s][c] : acc[s][c + 4];
            float mine = (lane & 4) ? acc[s][c + 4] : acc[s][c];
            acc[s][c] = mine + __shfl_xor(sent, 4, 64);
        }
        #pragma unroll
        for (int c = 0; c < 2; ++c) {
            float sent = (lane & 2) ? acc[s][c] : acc[s][c + 2];
            float mine = (lane & 2) ? acc[s][c + 2] : acc[s][c];
            acc[s][c] = mine + __shfl_xor(sent, 2, 64);
        }
        {
            float sent = (lane & 1) ? acc[s][0] : acc[s][1];
            float mine = (lane & 1) ? acc[s][1] : acc[s][0];
            acc[s][0] = mine + __shfl_xor(sent, 1, 64);
        }
    }
    // Route sample G to group G while finishing the cross-group reduction.
    const int g4 = (lane >> 4) & 1, g5 = (lane >> 5) & 1;
    float a01, a23, colsum;
    {
        float sent = g4 ? acc[0][0] : acc[1][0];
        float keep = g4 ? acc[1][0] : acc[0][0];
        a01 = keep + __shfl_xor(sent, 16, 64);
    }
    {
        float sent = g4 ? acc[2][0] : acc[3][0];
        float keep = g4 ? acc[3][0] : acc[2][0];
        a23 = keep + __shfl_xor(sent, 16, 64);
    }
    {
        float sent = g5 ? a01 : a23;
        float keep = g5 ? a23 : a01;
        colsum = keep + __shfl_xor(sent, 32, 64);   // group G owns sample G
    }

    part[wid][G][j] = colsum;
    __syncthreads();
    if (wid >= 2) return;

    // wave 0: samples bs+0..3 (waves 0+2); wave 1: samples bs+4..7 (1+3)
    colsum = part[wid][G][j] + part[wid + 2][G][j];

    float t0 = colsum + bin[j];
    float hj = t0 * rcpf(1.0f + expn(-t0));   // square_swish

    #pragma unroll
    for (int r = 0; r < cR; ++r) {
        const float* w1r = W1 + r * 256;
        const float* w2r = W2 + r * 256;
        float u = b1[r * 16 + j];
        #pragma unroll
        for (int i = 0; i < 16; ++i)
            u = fmaf(__shfl(hj, i, 16), w1r[i * 16 + j], u);
        u = u * rcpf(1.0f + expn(-u));
        float v = b2[r * 16 + j];
        #pragma unroll
        for (int i = 0; i < 16; ++i)
            v = fmaf(__shfl(u, i, 16), w2r[i * 16 + j], v);
        hj += v;
    }
    hbuf[(size_t)j * cB + (bs + wid * 4 + G)] = hj;   // transposed: [16][B]
}

// Invert the logistic-mixture logit per (sample b, dim d).
// Block = 256: 4 waves = 4 consecutive d (wave-uniform), lane = b in a 64-tile.
__global__ void __launch_bounds__(256) invert_kernel(
    float* __restrict__ z, const float* __restrict__ hbuf,
    const float* __restrict__ Wo, const float* __restrict__ bo,
    float* __restrict__ logq, int za_off)
{
    const int wid  = threadIdx.x >> 6;
    const int lane = threadIdx.x & 63;
    const int d = __builtin_amdgcn_readfirstlane(blockIdx.x * 4 + wid); // uniform
    const int b = blockIdx.y * 64 + lane;

    // h: 16 coalesced loads from transposed hbuf
    float hh[16];
    #pragma unroll
    for (int i = 0; i < 16; ++i) hh[i] = hbuf[(size_t)i * cB + b];

    // p[24] = bo[d*24+j] + sum_i h[i]*Wo[i*9408 + d*24 + j]  (Wo wave-uniform)
    float p[24];
    {
        const float4* bp = (const float4*)(bo + (size_t)d * 24);
        #pragma unroll
        for (int j4 = 0; j4 < 6; ++j4) {
            float4 v = bp[j4];
            p[j4*4+0] = v.x; p[j4*4+1] = v.y; p[j4*4+2] = v.z; p[j4*4+3] = v.w;
        }
        #pragma unroll
        for (int i = 0; i < 16; ++i) {
            float hv = hh[i];
            const float4* wr = (const float4*)(Wo + (size_t)i * cPDIM + (size_t)d * 24);
            #pragma unroll
            for (int j4 = 0; j4 < 6; ++j4) {
                float4 wv = wr[j4];
                p[j4*4+0] = fmaf(hv, wv.x, p[j4*4+0]);
                p[j4*4+1] = fmaf(hv, wv.y, p[j4*4+1]);
                p[j4*4+2] = fmaf(hv, wv.z, p[j4*4+2]);
                p[j4*4+3] = fmaf(hv, wv.w, p[j4*4+3]);
            }
        }
    }

    // Mirror: solve with mu_bar = sgn*mu, yb = |y|; x = sgn*x_bar.
    const float y0  = z[(size_t)b * cD + za_off + d];
    const float sgn = (y0 < 0.f) ? -1.f : 1.f;
    const float yb  = fabsf(y0);

    // Unnormalized softmax weights wt (sum S); per-k prescaled scales.
    float wt[8], pm[8], q2[8], is2[8], nm2[8], wis2[8];
    float S, lgSn, SLN2, lo, hi;
    {
        float m = p[0];
        #pragma unroll
        for (int k = 1; k < 8; ++k) m = fmaxf(m, p[k]);
        S = 0.f;
        #pragma unroll
        for (int k = 0; k < 8; ++k) {
            pm[k] = p[k] - m;
            wt[k] = exp2f_(pm[k] * L2E_F);
            S += wt[k];
        }
        lgSn = log2f_(S) * LN2_F;   // ln S
        SLN2 = S * LN2_F;
        float lo0 = 1e30f, hi0 = -1e30f;
        #pragma unroll
        for (int k = 0; k < 8; ++k) {
            q2[k] = p[16 + k] * L2E_F;          // log2 s_k
            float sk  = exp2f_(q2[k]);          // s_k
            float ik  = exp2f_(-q2[k]);         // 1/s_k
            is2[k] = ik * L2E_F;
            float mub = sgn * p[8 + k];
            nm2[k] = -mub * is2[k];
            wis2[k] = wt[k] * is2[k];
            float inv = fmaf(yb, sk, mub);      // mu_bar + s_k*yb
            lo0 = fminf(lo0, inv); hi0 = fmaxf(hi0, inv);
        }
        float pad = 1e-3f + 1e-5f * (fabsf(lo0) + fabsf(hi0));
        lo = lo0 - pad; hi = hi0 + pad;
    }

    float xv, ld;
    if (yb <= 30.0f) {
        // tau*S with tau = sigmoid(-yb) >= ~5e-14
        float et   = exp2f_(-yb * L2E_F);
        float tauS = et * rcpf(1.0f + et) * S;
        // --- 3 bisections; sn = 1/(1+exp2(t2)) is overflow-exact (inf->0)
        #pragma unroll 1
        for (int it = 0; it < 3; ++it) {
            float mid = 0.5f * (lo + hi);
            float sfv = 0.f;
            #pragma unroll
            for (int k = 0; k < 8; ++k) {
                float t2 = fmaf(mid, is2[k], nm2[k]);
                float e  = exp2f_(t2);
                float r  = rcpf(1.0f + e);
                sfv = fmaf(wt[k], r, sfv);
            }
            if (sfv > tauS) lo = mid; else hi = mid;   // sf decreasing in x
        }
        // --- 3 bracketed Newton steps (quadratic from bracket/8 midpoint)
        xv = 0.5f * (lo + hi);
        #pragma unroll 1
        for (int it = 0; it < 3; ++it) {
            float cdf = 0.f, sfv = 0.f, pdfa = 0.f;
            #pragma unroll
            for (int k = 0; k < 8; ++k) {
                float t2 = fmaf(xv, is2[k], nm2[k]);
                float e  = exp2f_(-fabsf(t2));
                float r  = rcpf(1.0f + e);
                float a  = e * r;
                float sp = (t2 >= 0.f) ? r : a;
                float sn = (t2 >= 0.f) ? a : r;
                cdf = fmaf(wt[k], sp, cdf);
                sfv = fmaf(wt[k], sn, sfv);
                pdfa = fmaf(wis2[k], sp * sn, pdfa);
            }
            float f = (log2f_(cdf) - log2f_(sfv)) * LN2_F;
            if (f < yb) lo = xv; else hi = xv;
            float step = (f - yb) * cdf * sfv * rcpf(pdfa * SLN2);
            float xn = xv - step;
            if (!(xn > lo && xn < hi)) xn = 0.5f * (lo + hi);
            xv = xn;
        }
        // --- peeled eval: ld at xv (pre-step; step ~ eps) + final step
        {
            float cdf = 0.f, sfv = 0.f, pdfa = 0.f;
            #pragma unroll
            for (int k = 0; k < 8; ++k) {
                float t2 = fmaf(xv, is2[k], nm2[k]);
                float e  = exp2f_(-fabsf(t2));
                float r  = rcpf(1.0f + e);
                float a  = e * r;
                float sp = (t2 >= 0.f) ? r : a;
                float sn = (t2 >= 0.f) ? a : r;
                cdf = fmaf(wt[k], sp, cdf);
                sfv = fmaf(wt[k], sn, sfv);
                pdfa = fmaf(wis2[k], sp * sn, pdfa);
            }
            float l2c = log2f_(cdf), l2s = log2f_(sfv), l2p = log2f_(pdfa);
            ld = (l2p - l2c - l2s) * LN2_F + LN_LN2_F + lgSn;
            float f = (l2c - l2s) * LN2_F;
            if (f < yb) lo = xv; else hi = xv;
            float step = (f - yb) * cdf * sfv * rcpf(pdfa * SLN2);
            float xn = xv - step;
            if (!(xn > lo && xn < hi)) xn = 0.5f * (lo + hi);
            xv = xn;
        }
    } else {
        // --- tail (yb>30): log-space LSE Newton from exact-bracket midpoint;
        // lc = log(1-sf) ~ -e^{-yb} ~ 0 (dropped, error < 1e-13).
        float lw[8], lis[8];
        #pragma unroll
        for (int k = 0; k < 8; ++k) {
            lw[k]  = pm[k] - lgSn;       // log softmax weight
            lis[k] = -q2[k] * LN2_F;     // -log s_k
        }
        xv = 0.5f * (lo + hi);
        #pragma unroll 1
        for (int it = 0; it < 4; ++it) {
            float u[8];
            float mu_ = -1e30f;
            #pragma unroll
            for (int k = 0; k < 8; ++k) {
                float t  = fmaf(xv, is2[k], nm2[k]) * LN2_F;  // natural t
                float ec = fminf(expn(-t), 1.0f);
                // log sigmoid(-t) = -t - log1p(e^{-t}) ~ -t - (ec - ec^2/2)
                u[k] = lw[k] - t - ec * fmaf(-0.5f, ec, 1.0f);
                mu_ = fmaxf(mu_, u[k]);
            }
            float Su = 0.f;
            #pragma unroll
            for (int k = 0; k < 8; ++k) Su += expn(u[k] - mu_);
            float lsf = mu_ + logn(Su);
            float m2 = -1e30f;
            #pragma unroll
            for (int k = 0; k < 8; ++k) m2 = fmaxf(m2, u[k] + lis[k]);
            float S2 = 0.f;
            #pragma unroll
            for (int k = 0; k < 8; ++k) S2 += expn(u[k] + lis[k] - m2);
            float lp = m2 + logn(S2);
            if (it == 3) { ld = lp - lsf; break; }
            float f = -lsf;                       // lc ~ 0
            if (f < yb) lo = xv; else hi = xv;
            float step = (f - yb) * expn(lsf - lp);
            float xn = xv - step;
            if (!(xn > lo && xn < hi)) xn = 0.5f * (lo + hi);
            xv = xn;
        }
    }

    z[(size_t)b * cD + za_off + d] = sgn * xv;

    // reduce ld over the 4 waves (4 d's) per b, one atomic per (block, b)
    __shared__ float red[256];
    red[threadIdx.x] = ld;
    __syncthreads();
    if (wid == 0) {
        float ssum = red[lane] + red[lane + 64] + red[lane + 128] + red[lane + 192];
        atomicAdd(&logq[b], ssum);
    }
}

extern "C" void kernel_launch(void* const* d_in, const int* in_sizes, int n_in,
                              void* d_out, int out_size, void* d_ws, size_t ws_size,
                              hipStream_t stream) {
    const float* x     = (const float*)d_in[0];
    const float* eps   = (const float*)d_in[1];
    const float* W_in  = (const float*)d_in[2];
    const float* b_in  = (const float*)d_in[3];
    const float* W1    = (const float*)d_in[4];
    const float* b1    = (const float*)d_in[5];
    const float* W2    = (const float*)d_in[6];
    const float* b2    = (const float*)d_in[7];
    const float* W_out = (const float*)d_in[8];
    const float* b_out = (const float*)d_in[9];

    float* z    = (float*)d_out;              // (B, D) working state = output z
    float* logq = z + (size_t)cB * cD;        // (B,)   output log_q
    float* hbuf = (float*)d_ws;               // (16, B) transposed scratch

    init_kernel<<<cB / 4, 256, 0, stream>>>(eps, z, logq);

    for (int l = cL - 1; l >= 0; --l) {
        const int zb_off = (l & 1) ? 0 : cD1;   // zb half offset within z row
        const int za_off = (l & 1) ? cD1 : 0;   // za half (overwritten in place)
        mlp_kernel<<<cB / 8, 256, 0, stream>>>(
            z, x,
            W_in + (size_t)l * cDIN * cH, b_in + (size_t)l * cH,
            W1 + (size_t)l * cR * cH * cH, b1 + (size_t)l * cR * cH,
            W2 + (size_t)l * cR * cH * cH, b2 + (size_t)l * cR * cH,
            hbuf, zb_off);
        invert_kernel<<<dim3(cD1 / 4, cB / 64), 256, 0, stream>>>(
            z, hbuf,
            W_out + (size_t)l * cH * cPDIM, b_out + (size_t)l * cPDIM,
            logq, za_off);
    }
}